// Round 1
// baseline (11527.221 us; speedup 1.0000x reference)
//
#include <hip/hip_runtime.h>

#define N_NODES 131072
#define DIM     128
#define NGRAPH  1024
#define NEDGE   4194304

typedef float floatx4 __attribute__((ext_vector_type(4)));

// ---------------------------------------------------------------- zero
__global__ __launch_bounds__(256)
void zero_kernel(floatx4* __restrict__ p, long n4) {
    long i = (long)blockIdx.x * blockDim.x + threadIdx.x;
    long stride = (long)gridDim.x * blockDim.x;
    floatx4 z = {0.f, 0.f, 0.f, 0.f};
    for (; i < n4; i += stride) p[i] = z;
}

// ---------------------------------------------------------------- layer 1
// x1[n] = sum_h ( relu(h1[h][n] @ W1[h] + b1[h]) @ W2[h] + b2[h] )
// h1[0] = concat(x, rw); h1[1..3] = hop features.
__global__ __launch_bounds__(256)
void layer1_kernel(const float* __restrict__ x, const float* __restrict__ rw,
                   const float* __restrict__ f1, const float* __restrict__ f2,
                   const float* __restrict__ f3,
                   const float* __restrict__ w1, const float* __restrict__ b1,
                   const float* __restrict__ w2, const float* __restrict__ b2,
                   float* __restrict__ x1out)
{
    __shared__ float tile[64 * 128];
    const int tid = threadIdx.x;
    const int tx = tid & 31;        // col group: cols c0..c0+3
    const int ty = tid >> 5;        // row group: rows ty*8..ty*8+7
    const int c0 = tx * 4;
    const int row0 = blockIdx.x * 64;

    float y[8][4];
#pragma unroll
    for (int i = 0; i < 8; ++i)
#pragma unroll
        for (int j = 0; j < 4; ++j) y[i][j] = 0.f;

    for (int h = 0; h < 4; ++h) {
        __syncthreads();
        // ---- stage A tile (64 rows x 128 cols)
        if (h == 0) {
#pragma unroll
            for (int it = 0; it < 8; ++it) {
                int f = tid + it * 256;      // float4 index, 32 per row
                int r = f >> 5;
                int colf = f & 31;
                const float* src = (colf < 16)
                    ? (x  + (size_t)(row0 + r) * 64 + colf * 4)
                    : (rw + (size_t)(row0 + r) * 64 + (colf - 16) * 4);
                *(floatx4*)&tile[f * 4] = *(const floatx4*)src;
            }
        } else {
            const float* feat = (h == 1) ? f1 : (h == 2) ? f2 : f3;
#pragma unroll
            for (int it = 0; it < 8; ++it) {
                int f = tid + it * 256;
                int r = f >> 5;
                int colf = f & 31;
                *(floatx4*)&tile[f * 4] =
                    *(const floatx4*)(feat + (size_t)(row0 + r) * 128 + colf * 4);
            }
        }
        __syncthreads();

        // ---- phase 1: acc = A @ W1[h]
        const float* W1h = w1 + h * 128 * 128;
        float acc[8][4];
#pragma unroll
        for (int i = 0; i < 8; ++i)
#pragma unroll
            for (int j = 0; j < 4; ++j) acc[i][j] = 0.f;

        for (int k = 0; k < 128; k += 4) {
            floatx4 wv[4];
#pragma unroll
            for (int kk = 0; kk < 4; ++kk)
                wv[kk] = *(const floatx4*)(W1h + (size_t)(k + kk) * 128 + c0);
#pragma unroll
            for (int i = 0; i < 8; ++i) {
                floatx4 a = *(const floatx4*)&tile[(ty * 8 + i) * 128 + k];
#pragma unroll
                for (int j = 0; j < 4; ++j)
                    acc[i][j] += a[0] * wv[0][j] + a[1] * wv[1][j]
                               + a[2] * wv[2][j] + a[3] * wv[3][j];
            }
        }

        // ---- bias + relu, Z back into LDS
        floatx4 bb = *(const floatx4*)(b1 + h * 128 + c0);
        __syncthreads();
#pragma unroll
        for (int i = 0; i < 8; ++i) {
            floatx4 z;
#pragma unroll
            for (int j = 0; j < 4; ++j) z[j] = fmaxf(acc[i][j] + bb[j], 0.f);
            *(floatx4*)&tile[(ty * 8 + i) * 128 + c0] = z;
        }
        __syncthreads();

        // ---- phase 2: y += Z @ W2[h]
        const float* W2h = w2 + h * 128 * 128;
        for (int k = 0; k < 128; k += 4) {
            floatx4 wv[4];
#pragma unroll
            for (int kk = 0; kk < 4; ++kk)
                wv[kk] = *(const floatx4*)(W2h + (size_t)(k + kk) * 128 + c0);
#pragma unroll
            for (int i = 0; i < 8; ++i) {
                floatx4 a = *(const floatx4*)&tile[(ty * 8 + i) * 128 + k];
#pragma unroll
                for (int j = 0; j < 4; ++j)
                    y[i][j] += a[0] * wv[0][j] + a[1] * wv[1][j]
                             + a[2] * wv[2][j] + a[3] * wv[3][j];
            }
        }
    }

    // ---- epilogue: + sum_h b2[h], store x1
    floatx4 b2s = {0.f, 0.f, 0.f, 0.f};
#pragma unroll
    for (int h = 0; h < 4; ++h) {
        floatx4 b = *(const floatx4*)(b2 + h * 128 + c0);
#pragma unroll
        for (int j = 0; j < 4; ++j) b2s[j] += b[j];
    }
#pragma unroll
    for (int i = 0; i < 8; ++i) {
        floatx4 o;
#pragma unroll
        for (int j = 0; j < 4; ++j) o[j] = y[i][j] + b2s[j];
        *(floatx4*)(x1out + (size_t)(row0 + ty * 8 + i) * 128 + c0) = o;
    }
}

// ---------------------------------------------------------------- spmm
// out[edges[0][e]] += xin[edges[1][e]]  (one wave per edge)
__global__ __launch_bounds__(256)
void spmm_kernel(const int* __restrict__ edges, const float* __restrict__ xin,
                 float* __restrict__ outb)
{
    const int lane = threadIdx.x & 63;
    const int wid = blockIdx.x * (blockDim.x >> 6) + (threadIdx.x >> 6);
    const int nw = gridDim.x * (blockDim.x >> 6);
    for (int e = wid; e < NEDGE; e += nw) {
        int r = edges[e];
        int c = edges[NEDGE + e];
        const float2 v = *(const float2*)(xin + (size_t)c * 128 + lane * 2);
        float* dst = outb + (size_t)r * 128 + lane * 2;
        atomicAdd(dst, v.x);
        atomicAdd(dst + 1, v.y);
    }
}

// ---------------------------------------------------------------- layer 2 + lin + pool
__global__ __launch_bounds__(256)
void layer2_kernel(const float* __restrict__ x1, const float* __restrict__ s1,
                   const float* __restrict__ s2, const float* __restrict__ s3,
                   const float* __restrict__ w1, const float* __restrict__ b1,
                   const float* __restrict__ w2, const float* __restrict__ b2,
                   const float* __restrict__ linw, const float* __restrict__ linb,
                   const int* __restrict__ batch, float* __restrict__ dout)
{
    __shared__ float tile[64 * 128];
    __shared__ int bsh[64];
    const int tid = threadIdx.x;
    const int tx = tid & 31;
    const int ty = tid >> 5;
    const int c0 = tx * 4;
    const int row0 = blockIdx.x * 64;

    float y[8][4];
#pragma unroll
    for (int i = 0; i < 8; ++i)
#pragma unroll
        for (int j = 0; j < 4; ++j) y[i][j] = 0.f;

    for (int h = 0; h < 4; ++h) {
        const float* feat = (h == 0) ? x1 : (h == 1) ? s1 : (h == 2) ? s2 : s3;
        __syncthreads();
#pragma unroll
        for (int it = 0; it < 8; ++it) {
            int f = tid + it * 256;
            int r = f >> 5;
            int colf = f & 31;
            *(floatx4*)&tile[f * 4] =
                *(const floatx4*)(feat + (size_t)(row0 + r) * 128 + colf * 4);
        }
        __syncthreads();

        const float* W1h = w1 + h * 128 * 128;
        float acc[8][4];
#pragma unroll
        for (int i = 0; i < 8; ++i)
#pragma unroll
            for (int j = 0; j < 4; ++j) acc[i][j] = 0.f;

        for (int k = 0; k < 128; k += 4) {
            floatx4 wv[4];
#pragma unroll
            for (int kk = 0; kk < 4; ++kk)
                wv[kk] = *(const floatx4*)(W1h + (size_t)(k + kk) * 128 + c0);
#pragma unroll
            for (int i = 0; i < 8; ++i) {
                floatx4 a = *(const floatx4*)&tile[(ty * 8 + i) * 128 + k];
#pragma unroll
                for (int j = 0; j < 4; ++j)
                    acc[i][j] += a[0] * wv[0][j] + a[1] * wv[1][j]
                               + a[2] * wv[2][j] + a[3] * wv[3][j];
            }
        }

        floatx4 bb = *(const floatx4*)(b1 + h * 128 + c0);
        __syncthreads();
#pragma unroll
        for (int i = 0; i < 8; ++i) {
            floatx4 z;
#pragma unroll
            for (int j = 0; j < 4; ++j) z[j] = fmaxf(acc[i][j] + bb[j], 0.f);
            *(floatx4*)&tile[(ty * 8 + i) * 128 + c0] = z;
        }
        __syncthreads();

        const float* W2h = w2 + h * 128 * 128;
        for (int k = 0; k < 128; k += 4) {
            floatx4 wv[4];
#pragma unroll
            for (int kk = 0; kk < 4; ++kk)
                wv[kk] = *(const floatx4*)(W2h + (size_t)(k + kk) * 128 + c0);
#pragma unroll
            for (int i = 0; i < 8; ++i) {
                floatx4 a = *(const floatx4*)&tile[(ty * 8 + i) * 128 + k];
#pragma unroll
                for (int j = 0; j < 4; ++j)
                    y[i][j] += a[0] * wv[0][j] + a[1] * wv[1][j]
                             + a[2] * wv[2][j] + a[3] * wv[3][j];
            }
        }
    }

    // y += sum_h b2[h]  -> x2 tile (in registers)
    floatx4 b2s = {0.f, 0.f, 0.f, 0.f};
#pragma unroll
    for (int h = 0; h < 4; ++h) {
        floatx4 b = *(const floatx4*)(b2 + h * 128 + c0);
#pragma unroll
        for (int j = 0; j < 4; ++j) b2s[j] += b[j];
    }
#pragma unroll
    for (int i = 0; i < 8; ++i)
#pragma unroll
        for (int j = 0; j < 4; ++j) y[i][j] += b2s[j];

    // ---- out = x1 @ linw[0:128] + x2 @ linw[128:256] + linb
    float o[8][4];
#pragma unroll
    for (int i = 0; i < 8; ++i)
#pragma unroll
        for (int j = 0; j < 4; ++j) o[i][j] = 0.f;

    // phase A: restage x1 tile
    __syncthreads();
#pragma unroll
    for (int it = 0; it < 8; ++it) {
        int f = tid + it * 256;
        int r = f >> 5;
        int colf = f & 31;
        *(floatx4*)&tile[f * 4] =
            *(const floatx4*)(x1 + (size_t)(row0 + r) * 128 + colf * 4);
    }
    __syncthreads();
    for (int k = 0; k < 128; k += 4) {
        floatx4 wv[4];
#pragma unroll
        for (int kk = 0; kk < 4; ++kk)
            wv[kk] = *(const floatx4*)(linw + (size_t)(k + kk) * 128 + c0);
#pragma unroll
        for (int i = 0; i < 8; ++i) {
            floatx4 a = *(const floatx4*)&tile[(ty * 8 + i) * 128 + k];
#pragma unroll
            for (int j = 0; j < 4; ++j)
                o[i][j] += a[0] * wv[0][j] + a[1] * wv[1][j]
                         + a[2] * wv[2][j] + a[3] * wv[3][j];
        }
    }

    // phase B: x2 tile
    __syncthreads();
#pragma unroll
    for (int i = 0; i < 8; ++i) {
        floatx4 z;
#pragma unroll
        for (int j = 0; j < 4; ++j) z[j] = y[i][j];
        *(floatx4*)&tile[(ty * 8 + i) * 128 + c0] = z;
    }
    __syncthreads();
    for (int k = 0; k < 128; k += 4) {
        floatx4 wv[4];
#pragma unroll
        for (int kk = 0; kk < 4; ++kk)
            wv[kk] = *(const floatx4*)(linw + (size_t)(128 + k + kk) * 128 + c0);
#pragma unroll
        for (int i = 0; i < 8; ++i) {
            floatx4 a = *(const floatx4*)&tile[(ty * 8 + i) * 128 + k];
#pragma unroll
            for (int j = 0; j < 4; ++j)
                o[i][j] += a[0] * wv[0][j] + a[1] * wv[1][j]
                         + a[2] * wv[2][j] + a[3] * wv[3][j];
        }
    }

    floatx4 lb = *(const floatx4*)(linb + c0);
#pragma unroll
    for (int i = 0; i < 8; ++i)
#pragma unroll
        for (int j = 0; j < 4; ++j) o[i][j] += lb[j];

    // ---- pool: write o tile to LDS, walk batch runs, atomic per segment
    __syncthreads();
#pragma unroll
    for (int i = 0; i < 8; ++i) {
        floatx4 z;
#pragma unroll
        for (int j = 0; j < 4; ++j) z[j] = o[i][j];
        *(floatx4*)&tile[(ty * 8 + i) * 128 + c0] = z;
    }
    if (tid < 64) bsh[tid] = batch[row0 + tid];
    __syncthreads();

    if (tid < 128) {
        const int d = tid;
        float acc = 0.f;
        int cur = bsh[0];
        for (int r = 0; r < 64; ++r) {
            int b = bsh[r];
            if (b != cur) {
                atomicAdd(dout + (size_t)cur * 128 + d, acc);
                acc = 0.f;
                cur = b;
            }
            acc += tile[r * 128 + d];
        }
        atomicAdd(dout + (size_t)cur * 128 + d, acc);
    }
}

// ---------------------------------------------------------------- launch
extern "C" void kernel_launch(void* const* d_in, const int* in_sizes, int n_in,
                              void* d_out, int out_size, void* d_ws, size_t ws_size,
                              hipStream_t stream) {
    (void)in_sizes; (void)n_in; (void)out_size; (void)ws_size;

    const float* x    = (const float*)d_in[0];
    const float* rw   = (const float*)d_in[1];
    const float* f1   = (const float*)d_in[2];
    const float* f2   = (const float*)d_in[3];
    const float* f3   = (const float*)d_in[4];
    const int*   e1   = (const int*)d_in[5];
    const int*   e2   = (const int*)d_in[6];
    const int*   e3   = (const int*)d_in[7];
    const int*   batch= (const int*)d_in[8];
    const float* l1w1 = (const float*)d_in[9];
    const float* l1b1 = (const float*)d_in[10];
    const float* l1w2 = (const float*)d_in[11];
    const float* l1b2 = (const float*)d_in[12];
    const float* l2w1 = (const float*)d_in[13];
    const float* l2b1 = (const float*)d_in[14];
    const float* l2w2 = (const float*)d_in[15];
    const float* l2b2 = (const float*)d_in[16];
    const float* linw = (const float*)d_in[17];
    const float* linb = (const float*)d_in[18];

    float* out = (float*)d_out;
    float* ws  = (float*)d_ws;
    float* x1  = ws;
    float* s1  = ws + (size_t)N_NODES * 128;
    float* s2  = s1 + (size_t)N_NODES * 128;
    float* s3  = s2 + (size_t)N_NODES * 128;

    // zero spmm accumulators + output (harness poisons, does not re-poison)
    zero_kernel<<<2048, 256, 0, stream>>>((floatx4*)s1, (long)3 * N_NODES * 32);
    zero_kernel<<<64, 256, 0, stream>>>((floatx4*)out, (long)NGRAPH * 32);

    layer1_kernel<<<N_NODES / 64, 256, 0, stream>>>(
        x, rw, f1, f2, f3, l1w1, l1b1, l1w2, l1b2, x1);

    spmm_kernel<<<8192, 256, 0, stream>>>(e1, x1, s1);
    spmm_kernel<<<8192, 256, 0, stream>>>(e2, x1, s2);
    spmm_kernel<<<8192, 256, 0, stream>>>(e3, x1, s3);

    layer2_kernel<<<N_NODES / 64, 256, 0, stream>>>(
        x1, s1, s2, s3, l2w1, l2b1, l2w2, l2b2, linw, linb, batch, out);
}

// Round 2
// 3631.813 us; speedup vs baseline: 3.1740x; 3.1740x over previous
//
#include <hip/hip_runtime.h>

#define N_NODES 131072
#define DIM     128
#define NGRAPH  1024
#define NEDGE   4194304

typedef float floatx4 __attribute__((ext_vector_type(4)));

// ---------------------------------------------------------------- zero
__global__ __launch_bounds__(256)
void zero_kernel(floatx4* __restrict__ p, long n4) {
    long i = (long)blockIdx.x * blockDim.x + threadIdx.x;
    long stride = (long)gridDim.x * blockDim.x;
    floatx4 z = {0.f, 0.f, 0.f, 0.f};
    for (; i < n4; i += stride) p[i] = z;
}

__global__ __launch_bounds__(256)
void zero_int_kernel(int* __restrict__ p, int n) {
    int i = blockIdx.x * blockDim.x + threadIdx.x;
    int stride = gridDim.x * blockDim.x;
    for (; i < n; i += stride) p[i] = 0;
}

// ---------------------------------------------------------------- CSR build
__global__ __launch_bounds__(256)
void hist_kernel(const int* __restrict__ rows, int* __restrict__ deg) {
    int i = blockIdx.x * blockDim.x + threadIdx.x;
    int stride = gridDim.x * blockDim.x;
    for (; i < NEDGE; i += stride) atomicAdd(&deg[rows[i]], 1);
}

// single block, 1024 threads; exclusive scan of deg[0..N) -> offs, cursor; offs[N]=total
__global__ __launch_bounds__(1024)
void scan_kernel(const int* __restrict__ deg, int* __restrict__ offs,
                 int* __restrict__ cursor) {
    __shared__ int part[1024];
    const int t = threadIdx.x;
    const int base = t * (N_NODES / 1024);
    int s = 0;
    for (int i = 0; i < N_NODES / 1024; ++i) s += deg[base + i];
    part[t] = s;
    __syncthreads();
    for (int d = 1; d < 1024; d <<= 1) {
        int v = (t >= d) ? part[t - d] : 0;
        __syncthreads();
        part[t] += v;
        __syncthreads();
    }
    int run = (t == 0) ? 0 : part[t - 1];
    for (int i = 0; i < N_NODES / 1024; ++i) {
        int idx = base + i;
        int d = deg[idx];
        offs[idx] = run;
        cursor[idx] = run;
        run += d;
    }
    if (t == 1023) offs[N_NODES] = run;
}

__global__ __launch_bounds__(256)
void scatter_kernel(const int* __restrict__ edges, int* __restrict__ cursor,
                    int* __restrict__ col) {
    int i = blockIdx.x * blockDim.x + threadIdx.x;
    int stride = gridDim.x * blockDim.x;
    for (; i < NEDGE; i += stride) {
        int r = edges[i];
        int c = edges[NEDGE + i];
        int p = atomicAdd(&cursor[r], 1);
        col[p] = c;
    }
}

// ---------------------------------------------------------------- CSR spmm
// one wave per destination row; gather + register accumulate; one write
__global__ __launch_bounds__(256)
void csr_spmm_kernel(const int* __restrict__ offs, const int* __restrict__ col,
                     const float* __restrict__ xin, float* __restrict__ outb) {
    const int lane = threadIdx.x & 63;
    const int row = blockIdx.x * (blockDim.x >> 6) + (threadIdx.x >> 6);
    if (row >= N_NODES) return;
    const int beg = offs[row];
    const int end = offs[row + 1];

    float2 a0 = {0.f, 0.f}, a1 = {0.f, 0.f};
    for (int b = beg; b < end; b += 64) {
        const int n = min(64, end - b);
        int cidx = (b + lane < end) ? col[b + lane] : 0;
        int i = 0;
        for (; i + 4 <= n; i += 4) {
            int c0 = __shfl(cidx, i);
            int c1 = __shfl(cidx, i + 1);
            int c2 = __shfl(cidx, i + 2);
            int c3 = __shfl(cidx, i + 3);
            float2 v0 = *(const float2*)(xin + (size_t)c0 * 128 + lane * 2);
            float2 v1 = *(const float2*)(xin + (size_t)c1 * 128 + lane * 2);
            float2 v2 = *(const float2*)(xin + (size_t)c2 * 128 + lane * 2);
            float2 v3 = *(const float2*)(xin + (size_t)c3 * 128 + lane * 2);
            a0.x += v0.x; a0.y += v0.y;
            a1.x += v1.x; a1.y += v1.y;
            a0.x += v2.x; a0.y += v2.y;
            a1.x += v3.x; a1.y += v3.y;
        }
        for (; i < n; ++i) {
            int c = __shfl(cidx, i);
            float2 v = *(const float2*)(xin + (size_t)c * 128 + lane * 2);
            a0.x += v.x; a0.y += v.y;
        }
    }
    float2 o = {a0.x + a1.x, a0.y + a1.y};
    *(float2*)(outb + (size_t)row * 128 + lane * 2) = o;
}

// ---------------------------------------------------------------- atomic spmm (fallback)
__global__ __launch_bounds__(256)
void spmm_kernel(const int* __restrict__ edges, const float* __restrict__ xin,
                 float* __restrict__ outb)
{
    const int lane = threadIdx.x & 63;
    const int wid = blockIdx.x * (blockDim.x >> 6) + (threadIdx.x >> 6);
    const int nw = gridDim.x * (blockDim.x >> 6);
    for (int e = wid; e < NEDGE; e += nw) {
        int r = edges[e];
        int c = edges[NEDGE + e];
        const float2 v = *(const float2*)(xin + (size_t)c * 128 + lane * 2);
        float* dst = outb + (size_t)r * 128 + lane * 2;
        atomicAdd(dst, v.x);
        atomicAdd(dst + 1, v.y);
    }
}

// ---------------------------------------------------------------- layer 1
__global__ __launch_bounds__(256)
void layer1_kernel(const float* __restrict__ x, const float* __restrict__ rw,
                   const float* __restrict__ f1, const float* __restrict__ f2,
                   const float* __restrict__ f3,
                   const float* __restrict__ w1, const float* __restrict__ b1,
                   const float* __restrict__ w2, const float* __restrict__ b2,
                   float* __restrict__ x1out)
{
    __shared__ float tile[64 * 128];
    const int tid = threadIdx.x;
    const int tx = tid & 31;
    const int ty = tid >> 5;
    const int c0 = tx * 4;
    const int row0 = blockIdx.x * 64;

    float y[8][4];
#pragma unroll
    for (int i = 0; i < 8; ++i)
#pragma unroll
        for (int j = 0; j < 4; ++j) y[i][j] = 0.f;

    for (int h = 0; h < 4; ++h) {
        __syncthreads();
        if (h == 0) {
#pragma unroll
            for (int it = 0; it < 8; ++it) {
                int f = tid + it * 256;
                int r = f >> 5;
                int colf = f & 31;
                const float* src = (colf < 16)
                    ? (x  + (size_t)(row0 + r) * 64 + colf * 4)
                    : (rw + (size_t)(row0 + r) * 64 + (colf - 16) * 4);
                *(floatx4*)&tile[f * 4] = *(const floatx4*)src;
            }
        } else {
            const float* feat = (h == 1) ? f1 : (h == 2) ? f2 : f3;
#pragma unroll
            for (int it = 0; it < 8; ++it) {
                int f = tid + it * 256;
                int r = f >> 5;
                int colf = f & 31;
                *(floatx4*)&tile[f * 4] =
                    *(const floatx4*)(feat + (size_t)(row0 + r) * 128 + colf * 4);
            }
        }
        __syncthreads();

        const float* W1h = w1 + h * 128 * 128;
        float acc[8][4];
#pragma unroll
        for (int i = 0; i < 8; ++i)
#pragma unroll
            for (int j = 0; j < 4; ++j) acc[i][j] = 0.f;

        for (int k = 0; k < 128; k += 4) {
            floatx4 wv[4];
#pragma unroll
            for (int kk = 0; kk < 4; ++kk)
                wv[kk] = *(const floatx4*)(W1h + (size_t)(k + kk) * 128 + c0);
#pragma unroll
            for (int i = 0; i < 8; ++i) {
                floatx4 a = *(const floatx4*)&tile[(ty * 8 + i) * 128 + k];
#pragma unroll
                for (int j = 0; j < 4; ++j)
                    acc[i][j] += a[0] * wv[0][j] + a[1] * wv[1][j]
                               + a[2] * wv[2][j] + a[3] * wv[3][j];
            }
        }

        floatx4 bb = *(const floatx4*)(b1 + h * 128 + c0);
        __syncthreads();
#pragma unroll
        for (int i = 0; i < 8; ++i) {
            floatx4 z;
#pragma unroll
            for (int j = 0; j < 4; ++j) z[j] = fmaxf(acc[i][j] + bb[j], 0.f);
            *(floatx4*)&tile[(ty * 8 + i) * 128 + c0] = z;
        }
        __syncthreads();

        const float* W2h = w2 + h * 128 * 128;
        for (int k = 0; k < 128; k += 4) {
            floatx4 wv[4];
#pragma unroll
            for (int kk = 0; kk < 4; ++kk)
                wv[kk] = *(const floatx4*)(W2h + (size_t)(k + kk) * 128 + c0);
#pragma unroll
            for (int i = 0; i < 8; ++i) {
                floatx4 a = *(const floatx4*)&tile[(ty * 8 + i) * 128 + k];
#pragma unroll
                for (int j = 0; j < 4; ++j)
                    y[i][j] += a[0] * wv[0][j] + a[1] * wv[1][j]
                             + a[2] * wv[2][j] + a[3] * wv[3][j];
            }
        }
    }

    floatx4 b2s = {0.f, 0.f, 0.f, 0.f};
#pragma unroll
    for (int h = 0; h < 4; ++h) {
        floatx4 b = *(const floatx4*)(b2 + h * 128 + c0);
#pragma unroll
        for (int j = 0; j < 4; ++j) b2s[j] += b[j];
    }
#pragma unroll
    for (int i = 0; i < 8; ++i) {
        floatx4 o;
#pragma unroll
        for (int j = 0; j < 4; ++j) o[j] = y[i][j] + b2s[j];
        *(floatx4*)(x1out + (size_t)(row0 + ty * 8 + i) * 128 + c0) = o;
    }
}

// ---------------------------------------------------------------- layer 2 + lin + pool
__global__ __launch_bounds__(256)
void layer2_kernel(const float* __restrict__ x1, const float* __restrict__ s1,
                   const float* __restrict__ s2, const float* __restrict__ s3,
                   const float* __restrict__ w1, const float* __restrict__ b1,
                   const float* __restrict__ w2, const float* __restrict__ b2,
                   const float* __restrict__ linw, const float* __restrict__ linb,
                   const int* __restrict__ batch, float* __restrict__ dout)
{
    __shared__ float tile[64 * 128];
    __shared__ int bsh[64];
    const int tid = threadIdx.x;
    const int tx = tid & 31;
    const int ty = tid >> 5;
    const int c0 = tx * 4;
    const int row0 = blockIdx.x * 64;

    float y[8][4];
#pragma unroll
    for (int i = 0; i < 8; ++i)
#pragma unroll
        for (int j = 0; j < 4; ++j) y[i][j] = 0.f;

    for (int h = 0; h < 4; ++h) {
        const float* feat = (h == 0) ? x1 : (h == 1) ? s1 : (h == 2) ? s2 : s3;
        __syncthreads();
#pragma unroll
        for (int it = 0; it < 8; ++it) {
            int f = tid + it * 256;
            int r = f >> 5;
            int colf = f & 31;
            *(floatx4*)&tile[f * 4] =
                *(const floatx4*)(feat + (size_t)(row0 + r) * 128 + colf * 4);
        }
        __syncthreads();

        const float* W1h = w1 + h * 128 * 128;
        float acc[8][4];
#pragma unroll
        for (int i = 0; i < 8; ++i)
#pragma unroll
            for (int j = 0; j < 4; ++j) acc[i][j] = 0.f;

        for (int k = 0; k < 128; k += 4) {
            floatx4 wv[4];
#pragma unroll
            for (int kk = 0; kk < 4; ++kk)
                wv[kk] = *(const floatx4*)(W1h + (size_t)(k + kk) * 128 + c0);
#pragma unroll
            for (int i = 0; i < 8; ++i) {
                floatx4 a = *(const floatx4*)&tile[(ty * 8 + i) * 128 + k];
#pragma unroll
                for (int j = 0; j < 4; ++j)
                    acc[i][j] += a[0] * wv[0][j] + a[1] * wv[1][j]
                               + a[2] * wv[2][j] + a[3] * wv[3][j];
            }
        }

        floatx4 bb = *(const floatx4*)(b1 + h * 128 + c0);
        __syncthreads();
#pragma unroll
        for (int i = 0; i < 8; ++i) {
            floatx4 z;
#pragma unroll
            for (int j = 0; j < 4; ++j) z[j] = fmaxf(acc[i][j] + bb[j], 0.f);
            *(floatx4*)&tile[(ty * 8 + i) * 128 + c0] = z;
        }
        __syncthreads();

        const float* W2h = w2 + h * 128 * 128;
        for (int k = 0; k < 128; k += 4) {
            floatx4 wv[4];
#pragma unroll
            for (int kk = 0; kk < 4; ++kk)
                wv[kk] = *(const floatx4*)(W2h + (size_t)(k + kk) * 128 + c0);
#pragma unroll
            for (int i = 0; i < 8; ++i) {
                floatx4 a = *(const floatx4*)&tile[(ty * 8 + i) * 128 + k];
#pragma unroll
                for (int j = 0; j < 4; ++j)
                    y[i][j] += a[0] * wv[0][j] + a[1] * wv[1][j]
                             + a[2] * wv[2][j] + a[3] * wv[3][j];
            }
        }
    }

    floatx4 b2s = {0.f, 0.f, 0.f, 0.f};
#pragma unroll
    for (int h = 0; h < 4; ++h) {
        floatx4 b = *(const floatx4*)(b2 + h * 128 + c0);
#pragma unroll
        for (int j = 0; j < 4; ++j) b2s[j] += b[j];
    }
#pragma unroll
    for (int i = 0; i < 8; ++i)
#pragma unroll
        for (int j = 0; j < 4; ++j) y[i][j] += b2s[j];

    float o[8][4];
#pragma unroll
    for (int i = 0; i < 8; ++i)
#pragma unroll
        for (int j = 0; j < 4; ++j) o[i][j] = 0.f;

    __syncthreads();
#pragma unroll
    for (int it = 0; it < 8; ++it) {
        int f = tid + it * 256;
        int r = f >> 5;
        int colf = f & 31;
        *(floatx4*)&tile[f * 4] =
            *(const floatx4*)(x1 + (size_t)(row0 + r) * 128 + colf * 4);
    }
    __syncthreads();
    for (int k = 0; k < 128; k += 4) {
        floatx4 wv[4];
#pragma unroll
        for (int kk = 0; kk < 4; ++kk)
            wv[kk] = *(const floatx4*)(linw + (size_t)(k + kk) * 128 + c0);
#pragma unroll
        for (int i = 0; i < 8; ++i) {
            floatx4 a = *(const floatx4*)&tile[(ty * 8 + i) * 128 + k];
#pragma unroll
            for (int j = 0; j < 4; ++j)
                o[i][j] += a[0] * wv[0][j] + a[1] * wv[1][j]
                         + a[2] * wv[2][j] + a[3] * wv[3][j];
        }
    }

    __syncthreads();
#pragma unroll
    for (int i = 0; i < 8; ++i) {
        floatx4 z;
#pragma unroll
        for (int j = 0; j < 4; ++j) z[j] = y[i][j];
        *(floatx4*)&tile[(ty * 8 + i) * 128 + c0] = z;
    }
    __syncthreads();
    for (int k = 0; k < 128; k += 4) {
        floatx4 wv[4];
#pragma unroll
        for (int kk = 0; kk < 4; ++kk)
            wv[kk] = *(const floatx4*)(linw + (size_t)(128 + k + kk) * 128 + c0);
#pragma unroll
        for (int i = 0; i < 8; ++i) {
            floatx4 a = *(const floatx4*)&tile[(ty * 8 + i) * 128 + k];
#pragma unroll
            for (int j = 0; j < 4; ++j)
                o[i][j] += a[0] * wv[0][j] + a[1] * wv[1][j]
                         + a[2] * wv[2][j] + a[3] * wv[3][j];
        }
    }

    floatx4 lb = *(const floatx4*)(linb + c0);
#pragma unroll
    for (int i = 0; i < 8; ++i)
#pragma unroll
        for (int j = 0; j < 4; ++j) o[i][j] += lb[j];

    __syncthreads();
#pragma unroll
    for (int i = 0; i < 8; ++i) {
        floatx4 z;
#pragma unroll
        for (int j = 0; j < 4; ++j) z[j] = o[i][j];
        *(floatx4*)&tile[(ty * 8 + i) * 128 + c0] = z;
    }
    if (tid < 64) bsh[tid] = batch[row0 + tid];
    __syncthreads();

    if (tid < 128) {
        const int d = tid;
        float acc = 0.f;
        int cur = bsh[0];
        for (int r = 0; r < 64; ++r) {
            int b = bsh[r];
            if (b != cur) {
                atomicAdd(dout + (size_t)cur * 128 + d, acc);
                acc = 0.f;
                cur = b;
            }
            acc += tile[r * 128 + d];
        }
        atomicAdd(dout + (size_t)cur * 128 + d, acc);
    }
}

// ---------------------------------------------------------------- launch
extern "C" void kernel_launch(void* const* d_in, const int* in_sizes, int n_in,
                              void* d_out, int out_size, void* d_ws, size_t ws_size,
                              hipStream_t stream) {
    (void)in_sizes; (void)n_in; (void)out_size;

    const float* x    = (const float*)d_in[0];
    const float* rw   = (const float*)d_in[1];
    const float* f1   = (const float*)d_in[2];
    const float* f2   = (const float*)d_in[3];
    const float* f3   = (const float*)d_in[4];
    const int*   e1   = (const int*)d_in[5];
    const int*   e2   = (const int*)d_in[6];
    const int*   e3   = (const int*)d_in[7];
    const int*   batch= (const int*)d_in[8];
    const float* l1w1 = (const float*)d_in[9];
    const float* l1b1 = (const float*)d_in[10];
    const float* l1w2 = (const float*)d_in[11];
    const float* l1b2 = (const float*)d_in[12];
    const float* l2w1 = (const float*)d_in[13];
    const float* l2b1 = (const float*)d_in[14];
    const float* l2w2 = (const float*)d_in[15];
    const float* l2b2 = (const float*)d_in[16];
    const float* linw = (const float*)d_in[17];
    const float* linb = (const float*)d_in[18];

    float* out = (float*)d_out;
    float* ws  = (float*)d_ws;
    float* x1  = ws;
    float* s1  = ws + (size_t)N_NODES * 128;
    float* s2  = s1 + (size_t)N_NODES * 128;
    float* s3  = s2 + (size_t)N_NODES * 128;

    // CSR scratch after the 4 big buffers
    int* ibase  = (int*)(s3 + (size_t)N_NODES * 128);
    int* deg    = ibase;                    // N
    int* offs   = deg + N_NODES;            // N+1
    int* cursor = offs + N_NODES + 1;       // N
    int* col    = cursor + N_NODES;         // NEDGE
    size_t need = (size_t)4 * N_NODES * 128 * 4
                + ((size_t)3 * N_NODES + 1 + NEDGE) * 4;

    zero_kernel<<<64, 256, 0, stream>>>((floatx4*)out, (long)NGRAPH * 32);

    layer1_kernel<<<N_NODES / 64, 256, 0, stream>>>(
        x, rw, f1, f2, f3, l1w1, l1b1, l1w2, l1b2, x1);

    if (ws_size >= need) {
        const int* es[3] = {e1, e2, e3};
        float* ss[3] = {s1, s2, s3};
        for (int hop = 0; hop < 3; ++hop) {
            zero_int_kernel<<<128, 256, 0, stream>>>(deg, N_NODES);
            hist_kernel<<<4096, 256, 0, stream>>>(es[hop], deg);
            scan_kernel<<<1, 1024, 0, stream>>>(deg, offs, cursor);
            scatter_kernel<<<4096, 256, 0, stream>>>(es[hop], cursor, col);
            csr_spmm_kernel<<<N_NODES / 4, 256, 0, stream>>>(offs, col, x1, ss[hop]);
        }
    } else {
        // fallback: atomic scatter spmm
        zero_kernel<<<2048, 256, 0, stream>>>((floatx4*)s1, (long)3 * N_NODES * 32);
        spmm_kernel<<<8192, 256, 0, stream>>>(e1, x1, s1);
        spmm_kernel<<<8192, 256, 0, stream>>>(e2, x1, s2);
        spmm_kernel<<<8192, 256, 0, stream>>>(e3, x1, s3);
    }

    layer2_kernel<<<N_NODES / 64, 256, 0, stream>>>(
        x1, s1, s2, s3, l2w1, l2b1, l2w2, l2b2, linw, linb, batch, out);
}

// Round 3
// 2333.535 us; speedup vs baseline: 4.9398x; 1.5564x over previous
//
#include <hip/hip_runtime.h>

#define N_NODES 131072
#define DIM     128
#define NGRAPH  1024
#define NEDGE   4194304

typedef float floatx4 __attribute__((ext_vector_type(4)));
typedef float f32x4  __attribute__((ext_vector_type(4)));
typedef __bf16 bf16x8 __attribute__((ext_vector_type(8)));
typedef __bf16 bf16x4 __attribute__((ext_vector_type(4)));

// swizzled LDS byte offset for a [rows][128] bf16 tile (row stride 256 B)
__device__ __forceinline__ int lds_off(int row, int kb) {
    return row * 256 + (kb ^ ((row & 7) << 4));
}

// ---------------------------------------------------------------- zero
__global__ __launch_bounds__(256)
void zero_kernel(floatx4* __restrict__ p, long n4) {
    long i = (long)blockIdx.x * blockDim.x + threadIdx.x;
    long stride = (long)gridDim.x * blockDim.x;
    floatx4 z = {0.f, 0.f, 0.f, 0.f};
    for (; i < n4; i += stride) p[i] = z;
}

__global__ __launch_bounds__(256)
void zero_int_kernel(int* __restrict__ p, int n) {
    int i = blockIdx.x * blockDim.x + threadIdx.x;
    int stride = gridDim.x * blockDim.x;
    for (; i < n; i += stride) p[i] = 0;
}

// ---------------------------------------------------------------- weight prep
// src: nmat matrices [128][128] fp32 row-major (k, col)
// dst: nmat matrices [128][128] bf16, transposed: dst[m][col][k] = src[m][k][col]
__global__ __launch_bounds__(256)
void tr_kernel(const float* __restrict__ src, __bf16* __restrict__ dst, int nmat) {
    int idx = blockIdx.x * blockDim.x + threadIdx.x;
    int total = nmat * 16384;
    if (idx >= total) return;
    int m = idx >> 14;
    int col = (idx >> 7) & 127;
    int k = idx & 127;
    dst[idx] = (__bf16)src[m * 16384 + k * 128 + col];
}

// ---------------------------------------------------------------- CSR build
__global__ __launch_bounds__(256)
void hist_kernel(const int* __restrict__ rows, int* __restrict__ deg) {
    int i = blockIdx.x * blockDim.x + threadIdx.x;
    int stride = gridDim.x * blockDim.x;
    for (; i < NEDGE; i += stride) atomicAdd(&deg[rows[i]], 1);
}

__global__ __launch_bounds__(1024)
void scan_kernel(const int* __restrict__ deg, int* __restrict__ offs,
                 int* __restrict__ cursor) {
    __shared__ int part[1024];
    const int t = threadIdx.x;
    const int base = t * (N_NODES / 1024);
    int s = 0;
    for (int i = 0; i < N_NODES / 1024; ++i) s += deg[base + i];
    part[t] = s;
    __syncthreads();
    for (int d = 1; d < 1024; d <<= 1) {
        int v = (t >= d) ? part[t - d] : 0;
        __syncthreads();
        part[t] += v;
        __syncthreads();
    }
    int run = (t == 0) ? 0 : part[t - 1];
    for (int i = 0; i < N_NODES / 1024; ++i) {
        int idx = base + i;
        int d = deg[idx];
        offs[idx] = run;
        cursor[idx] = run;
        run += d;
    }
    if (t == 1023) offs[N_NODES] = run;
}

__global__ __launch_bounds__(256)
void scatter_kernel(const int* __restrict__ edges, int* __restrict__ cursor,
                    int* __restrict__ col) {
    int i = blockIdx.x * blockDim.x + threadIdx.x;
    int stride = gridDim.x * blockDim.x;
    for (; i < NEDGE; i += stride) {
        int r = edges[i];
        int c = edges[NEDGE + i];
        int p = atomicAdd(&cursor[r], 1);
        col[p] = c;
    }
}

// ---------------------------------------------------------------- CSR spmm (bf16)
__global__ __launch_bounds__(256)
void csr_spmm_kernel(const int* __restrict__ offs, const int* __restrict__ col,
                     const __bf16* __restrict__ xin, __bf16* __restrict__ outb) {
    const int lane = threadIdx.x & 63;
    const int row = blockIdx.x * (blockDim.x >> 6) + (threadIdx.x >> 6);
    if (row >= N_NODES) return;
    const int beg = offs[row];
    const int end = offs[row + 1];

    float a0 = 0.f, a1 = 0.f, b0 = 0.f, b1 = 0.f;
    float c0f = 0.f, c1f = 0.f, d0 = 0.f, d1 = 0.f;
    for (int b = beg; b < end; b += 64) {
        const int n = min(64, end - b);
        int cidx = (b + lane < end) ? col[b + lane] : 0;
        int i = 0;
        for (; i + 4 <= n; i += 4) {
            int e0 = __shfl(cidx, i);
            int e1 = __shfl(cidx, i + 1);
            int e2 = __shfl(cidx, i + 2);
            int e3 = __shfl(cidx, i + 3);
            unsigned v0 = *(const unsigned*)(xin + (size_t)e0 * 128 + lane * 2);
            unsigned v1 = *(const unsigned*)(xin + (size_t)e1 * 128 + lane * 2);
            unsigned v2 = *(const unsigned*)(xin + (size_t)e2 * 128 + lane * 2);
            unsigned v3 = *(const unsigned*)(xin + (size_t)e3 * 128 + lane * 2);
            a0 += __uint_as_float(v0 << 16); a1 += __uint_as_float(v0 & 0xffff0000u);
            b0 += __uint_as_float(v1 << 16); b1 += __uint_as_float(v1 & 0xffff0000u);
            c0f += __uint_as_float(v2 << 16); c1f += __uint_as_float(v2 & 0xffff0000u);
            d0 += __uint_as_float(v3 << 16); d1 += __uint_as_float(v3 & 0xffff0000u);
        }
        for (; i < n; ++i) {
            int e = __shfl(cidx, i);
            unsigned v = *(const unsigned*)(xin + (size_t)e * 128 + lane * 2);
            a0 += __uint_as_float(v << 16); a1 += __uint_as_float(v & 0xffff0000u);
        }
    }
    float o0 = a0 + b0 + c0f + d0;
    float o1 = a1 + b1 + c1f + d1;
    union { unsigned u; __bf16 h[2]; } pk;
    pk.h[0] = (__bf16)o0; pk.h[1] = (__bf16)o1;
    *(unsigned*)(outb + (size_t)row * 128 + lane * 2) = pk.u;
}

// ---------------------------------------------------------------- staging helpers
// stage 128x128 bf16 tile (global, row-major contiguous) -> swizzled LDS
__device__ __forceinline__ void stage_bf16_tile(char* dst, const __bf16* src, int tid) {
#pragma unroll
    for (int it = 0; it < 8; ++it) {
        int c = tid + it * 256;
        int r = c >> 4, o = c & 15;
        uint4 v = *(const uint4*)(src + (size_t)r * 128 + o * 8);
        *(uint4*)(dst + lds_off(r, o * 16)) = v;
    }
}

// stage 128x128 fp32 tile -> bf16 swizzled LDS
__device__ __forceinline__ void stage_f32_tile(char* dst, const float* src, int tid) {
#pragma unroll
    for (int it = 0; it < 16; ++it) {
        int c = tid + it * 256;
        int r = c >> 5, o = c & 31;
        floatx4 v = *(const floatx4*)(src + (size_t)r * 128 + o * 4);
        bf16x4 h;
        h[0] = (__bf16)v[0]; h[1] = (__bf16)v[1];
        h[2] = (__bf16)v[2]; h[3] = (__bf16)v[3];
        *(bf16x4*)(dst + lds_off(r, o * 8)) = h;
    }
}

// one 128rows x 128cols GEMM accumulate: acc[mt][n] += A_lds @ W_lds
__device__ __forceinline__ void mfma_phase(const char* az, const char* wb,
                                           int r0, int lrow, int grp,
                                           f32x4 (&acc)[2][8]) {
    bf16x8 am[2][4];
#pragma unroll
    for (int mt = 0; mt < 2; ++mt)
#pragma unroll
        for (int kk = 0; kk < 4; ++kk)
            am[mt][kk] = *(const bf16x8*)(az + lds_off(r0 + mt * 16 + lrow,
                                                       kk * 64 + grp * 16));
#pragma unroll
    for (int kk = 0; kk < 4; ++kk)
#pragma unroll
        for (int n = 0; n < 8; ++n) {
            bf16x8 b = *(const bf16x8*)(wb + lds_off(n * 16 + lrow,
                                                     kk * 64 + grp * 16));
#pragma unroll
            for (int mt = 0; mt < 2; ++mt)
                acc[mt][n] = __builtin_amdgcn_mfma_f32_16x16x32_bf16(
                    am[mt][kk], b, acc[mt][n], 0, 0, 0);
        }
}

// ---------------------------------------------------------------- layer 1 (MFMA)
__global__ __launch_bounds__(256, 2)
void layer1_kernel(const float* __restrict__ x, const float* __restrict__ rw,
                   const float* __restrict__ f1, const float* __restrict__ f2,
                   const float* __restrict__ f3,
                   const __bf16* __restrict__ wt1, const float* __restrict__ b1,
                   const __bf16* __restrict__ wt2, const float* __restrict__ b2,
                   __bf16* __restrict__ x1out)
{
    __shared__ uint4 lds_u4[4096];            // 64 KiB
    char* AZ = (char*)lds_u4;                 // 32 KiB: A tile / Z tile
    char* WB = (char*)lds_u4 + 32768;         // 32 KiB: weight tile
    const int tid = threadIdx.x;
    const int lane = tid & 63;
    const int w = tid >> 6;
    const int r0 = w * 32;
    const int lrow = lane & 15;
    const int grp = lane >> 4;
    const int row0 = blockIdx.x * 128;

    f32x4 Y[2][8];
#pragma unroll
    for (int mt = 0; mt < 2; ++mt)
#pragma unroll
        for (int n = 0; n < 8; ++n) Y[mt][n] = {0.f, 0.f, 0.f, 0.f};

    for (int h = 0; h < 4; ++h) {
        __syncthreads();
        // stage A (feat h) fp32 -> bf16 LDS
        if (h == 0) {
#pragma unroll
            for (int it = 0; it < 16; ++it) {
                int c = tid + it * 256;
                int r = c >> 5, o = c & 31;
                const float* src = (o < 16)
                    ? (x  + (size_t)(row0 + r) * 64 + o * 4)
                    : (rw + (size_t)(row0 + r) * 64 + (o - 16) * 4);
                floatx4 v = *(const floatx4*)src;
                bf16x4 hh;
                hh[0] = (__bf16)v[0]; hh[1] = (__bf16)v[1];
                hh[2] = (__bf16)v[2]; hh[3] = (__bf16)v[3];
                *(bf16x4*)(AZ + lds_off(r, o * 8)) = hh;
            }
        } else {
            const float* feat = (h == 1) ? f1 : (h == 2) ? f2 : f3;
            stage_f32_tile(AZ, feat + (size_t)row0 * 128, tid);
        }
        stage_bf16_tile(WB, wt1 + (size_t)h * 16384, tid);
        __syncthreads();

        // phase 1: acc1 = A @ W1[h]
        f32x4 acc1[2][8];
#pragma unroll
        for (int mt = 0; mt < 2; ++mt)
#pragma unroll
            for (int n = 0; n < 8; ++n) acc1[mt][n] = {0.f, 0.f, 0.f, 0.f};
        mfma_phase(AZ, WB, r0, lrow, grp, acc1);

        // bias + relu -> Z into AZ (wave-private rows)
#pragma unroll
        for (int n = 0; n < 8; ++n) {
            float bias = b1[h * 128 + n * 16 + lrow];
#pragma unroll
            for (int mt = 0; mt < 2; ++mt)
#pragma unroll
                for (int rg = 0; rg < 4; ++rg) {
                    float v = fmaxf(acc1[mt][n][rg] + bias, 0.f);
                    int zr = r0 + mt * 16 + grp * 4 + rg;
                    *(__bf16*)(AZ + lds_off(zr, (n * 16 + lrow) * 2)) = (__bf16)v;
                }
        }
        __syncthreads();
        stage_bf16_tile(WB, wt2 + (size_t)h * 16384, tid);
        __syncthreads();

        // phase 2: Y += Z @ W2[h]
        mfma_phase(AZ, WB, r0, lrow, grp, Y);
    }

    // epilogue: + sum_h b2, store x1 (bf16)
#pragma unroll
    for (int n = 0; n < 8; ++n) {
        int cc = n * 16 + lrow;
        float bs = b2[cc] + b2[128 + cc] + b2[256 + cc] + b2[384 + cc];
#pragma unroll
        for (int mt = 0; mt < 2; ++mt)
#pragma unroll
            for (int rg = 0; rg < 4; ++rg) {
                int gr = row0 + r0 + mt * 16 + grp * 4 + rg;
                x1out[(size_t)gr * 128 + cc] = (__bf16)(Y[mt][n][rg] + bs);
            }
    }
}

// ---------------------------------------------------------------- layer 2 + lin + pool (MFMA)
__global__ __launch_bounds__(256, 2)
void layer2_kernel(const __bf16* __restrict__ x1b, const __bf16* __restrict__ s1,
                   const __bf16* __restrict__ s2, const __bf16* __restrict__ s3,
                   const __bf16* __restrict__ wt1, const float* __restrict__ b1,
                   const __bf16* __restrict__ wt2, const float* __restrict__ b2,
                   const __bf16* __restrict__ wtl, const float* __restrict__ linb,
                   const int* __restrict__ batch, float* __restrict__ dout)
{
    __shared__ uint4 lds_u4[4096];            // 64 KiB
    char* AZ = (char*)lds_u4;
    char* WB = (char*)lds_u4 + 32768;
    const int tid = threadIdx.x;
    const int lane = tid & 63;
    const int w = tid >> 6;
    const int r0 = w * 32;
    const int lrow = lane & 15;
    const int grp = lane >> 4;
    const int row0 = blockIdx.x * 128;

    f32x4 Y[2][8];
#pragma unroll
    for (int mt = 0; mt < 2; ++mt)
#pragma unroll
        for (int n = 0; n < 8; ++n) Y[mt][n] = {0.f, 0.f, 0.f, 0.f};

    for (int h = 0; h < 4; ++h) {
        const __bf16* feat = (h == 0) ? x1b : (h == 1) ? s1 : (h == 2) ? s2 : s3;
        __syncthreads();
        stage_bf16_tile(AZ, feat + (size_t)row0 * 128, tid);
        stage_bf16_tile(WB, wt1 + (size_t)h * 16384, tid);
        __syncthreads();

        f32x4 acc1[2][8];
#pragma unroll
        for (int mt = 0; mt < 2; ++mt)
#pragma unroll
            for (int n = 0; n < 8; ++n) acc1[mt][n] = {0.f, 0.f, 0.f, 0.f};
        mfma_phase(AZ, WB, r0, lrow, grp, acc1);

#pragma unroll
        for (int n = 0; n < 8; ++n) {
            float bias = b1[h * 128 + n * 16 + lrow];
#pragma unroll
            for (int mt = 0; mt < 2; ++mt)
#pragma unroll
                for (int rg = 0; rg < 4; ++rg) {
                    float v = fmaxf(acc1[mt][n][rg] + bias, 0.f);
                    int zr = r0 + mt * 16 + grp * 4 + rg;
                    *(__bf16*)(AZ + lds_off(zr, (n * 16 + lrow) * 2)) = (__bf16)v;
                }
        }
        __syncthreads();
        stage_bf16_tile(WB, wt2 + (size_t)h * 16384, tid);
        __syncthreads();
        mfma_phase(AZ, WB, r0, lrow, grp, Y);
    }

    // x2 = Y + sum_h b2 -> bf16 into AZ (wave-private rows)
#pragma unroll
    for (int n = 0; n < 8; ++n) {
        int cc = n * 16 + lrow;
        float bs = b2[cc] + b2[128 + cc] + b2[256 + cc] + b2[384 + cc];
#pragma unroll
        for (int mt = 0; mt < 2; ++mt)
#pragma unroll
            for (int rg = 0; rg < 4; ++rg) {
                float v = Y[mt][n][rg] + bs;
                int zr = r0 + mt * 16 + grp * 4 + rg;
                *(__bf16*)(AZ + lds_off(zr, (n * 16 + lrow) * 2)) = (__bf16)v;
            }
    }
    __syncthreads();                      // all phase-2 WB reads done
    stage_bf16_tile(WB, wtl + 16384, tid);   // lin weights for x2 part
    __syncthreads();

    f32x4 o[2][8];
#pragma unroll
    for (int mt = 0; mt < 2; ++mt)
#pragma unroll
        for (int n = 0; n < 8; ++n) o[mt][n] = {0.f, 0.f, 0.f, 0.f};
    mfma_phase(AZ, WB, r0, lrow, grp, o);    // o = x2 @ lin1

    __syncthreads();                      // AZ(x2)/WB reads done
    stage_bf16_tile(AZ, x1b + (size_t)row0 * 128, tid);
    stage_bf16_tile(WB, wtl, tid);           // lin weights for x1 part
    __syncthreads();
    mfma_phase(AZ, WB, r0, lrow, grp, o);    // o += x1 @ lin0

    // + linb, write to fp32 pool tile (full 64 KiB LDS)
    __syncthreads();                      // all LDS reads done before overwrite
    float* tile32 = (float*)lds_u4;
#pragma unroll
    for (int n = 0; n < 8; ++n) {
        int cc = n * 16 + lrow;
        float lb = linb[cc];
#pragma unroll
        for (int mt = 0; mt < 2; ++mt)
#pragma unroll
            for (int rg = 0; rg < 4; ++rg) {
                int rl = r0 + mt * 16 + grp * 4 + rg;
                tile32[rl * 128 + cc] = o[mt][n][rg] + lb;
            }
    }
    __syncthreads();

    // pool: batch is sorted; walk 128 rows, one atomic per segment boundary
    if (tid < 128) {
        const int d = tid;
        float acc = 0.f;
        int cur = batch[row0];
        for (int r = 0; r < 128; ++r) {
            int b = batch[row0 + r];
            if (b != cur) {
                atomicAdd(dout + (size_t)cur * 128 + d, acc);
                acc = 0.f;
                cur = b;
            }
            acc += tile32[r * 128 + d];
        }
        atomicAdd(dout + (size_t)cur * 128 + d, acc);
    }
}

// ---------------------------------------------------------------- launch
extern "C" void kernel_launch(void* const* d_in, const int* in_sizes, int n_in,
                              void* d_out, int out_size, void* d_ws, size_t ws_size,
                              hipStream_t stream) {
    (void)in_sizes; (void)n_in; (void)out_size; (void)ws_size;

    const float* x    = (const float*)d_in[0];
    const float* rw   = (const float*)d_in[1];
    const float* f1   = (const float*)d_in[2];
    const float* f2   = (const float*)d_in[3];
    const float* f3   = (const float*)d_in[4];
    const int*   e1   = (const int*)d_in[5];
    const int*   e2   = (const int*)d_in[6];
    const int*   e3   = (const int*)d_in[7];
    const int*   batch= (const int*)d_in[8];
    const float* l1w1 = (const float*)d_in[9];
    const float* l1b1 = (const float*)d_in[10];
    const float* l1w2 = (const float*)d_in[11];
    const float* l1b2 = (const float*)d_in[12];
    const float* l2w1 = (const float*)d_in[13];
    const float* l2b1 = (const float*)d_in[14];
    const float* l2w2 = (const float*)d_in[15];
    const float* l2b2 = (const float*)d_in[16];
    const float* linw = (const float*)d_in[17];
    const float* linb = (const float*)d_in[18];

    float* out = (float*)d_out;

    // workspace layout (all bf16 data plane)
    __bf16* x1b = (__bf16*)d_ws;
    __bf16* s1b = x1b + (size_t)N_NODES * 128;
    __bf16* s2b = s1b + (size_t)N_NODES * 128;
    __bf16* s3b = s2b + (size_t)N_NODES * 128;
    __bf16* wt  = s3b + (size_t)N_NODES * 128;   // 18 * 16384 bf16
    __bf16* wt_l1w1 = wt;
    __bf16* wt_l1w2 = wt + 4 * 16384;
    __bf16* wt_l2w1 = wt + 8 * 16384;
    __bf16* wt_l2w2 = wt + 12 * 16384;
    __bf16* wt_lin  = wt + 16 * 16384;
    int* ibase  = (int*)(wt + 18 * 16384);
    int* deg    = ibase;
    int* offs   = deg + N_NODES;
    int* cursor = offs + N_NODES + 1;
    int* col    = cursor + N_NODES;

    // weights -> bf16 transposed
    tr_kernel<<<256, 256, 0, stream>>>(l1w1, wt_l1w1, 4);
    tr_kernel<<<256, 256, 0, stream>>>(l1w2, wt_l1w2, 4);
    tr_kernel<<<256, 256, 0, stream>>>(l2w1, wt_l2w1, 4);
    tr_kernel<<<256, 256, 0, stream>>>(l2w2, wt_l2w2, 4);
    tr_kernel<<<128, 256, 0, stream>>>(linw, wt_lin, 2);

    zero_kernel<<<64, 256, 0, stream>>>((floatx4*)out, (long)NGRAPH * 32);

    layer1_kernel<<<N_NODES / 128, 256, 0, stream>>>(
        x, rw, f1, f2, f3, wt_l1w1, l1b1, wt_l1w2, l1b2, x1b);

    const int* es[3] = {e1, e2, e3};
    __bf16* ss[3] = {s1b, s2b, s3b};
    for (int hop = 0; hop < 3; ++hop) {
        zero_int_kernel<<<128, 256, 0, stream>>>(deg, N_NODES);
        hist_kernel<<<4096, 256, 0, stream>>>(es[hop], deg);
        scan_kernel<<<1, 1024, 0, stream>>>(deg, offs, cursor);
        scatter_kernel<<<4096, 256, 0, stream>>>(es[hop], cursor, col);
        csr_spmm_kernel<<<N_NODES / 4, 256, 0, stream>>>(offs, col, x1b, ss[hop]);
    }

    layer2_kernel<<<N_NODES / 128, 256, 0, stream>>>(
        x1b, s1b, s2b, s3b, wt_l2w1, l2b1, wt_l2w2, l2b2, wt_lin, linb, batch, out);
}

// Round 4
// 1970.050 us; speedup vs baseline: 5.8512x; 1.1845x over previous
//
#include <hip/hip_runtime.h>

#define N_NODES 131072
#define DIM     128
#define NGRAPH  1024
#define NEDGE   4194304
#define SC_PASS 8
#define SC_WIN  (N_NODES / SC_PASS)   // 16384 rows -> ~2MB col window

typedef float floatx4 __attribute__((ext_vector_type(4)));
typedef float f32x4  __attribute__((ext_vector_type(4)));
typedef __bf16 bf16x8 __attribute__((ext_vector_type(8)));
typedef __bf16 bf16x4 __attribute__((ext_vector_type(4)));

// swizzled LDS byte offset for a [rows][128] bf16 tile (row stride 256 B)
__device__ __forceinline__ int lds_off(int row, int kb) {
    return row * 256 + (kb ^ ((row & 7) << 4));
}

// ---------------------------------------------------------------- zero
__global__ __launch_bounds__(256)
void zero_kernel(floatx4* __restrict__ p, long n4) {
    long i = (long)blockIdx.x * blockDim.x + threadIdx.x;
    long stride = (long)gridDim.x * blockDim.x;
    floatx4 z = {0.f, 0.f, 0.f, 0.f};
    for (; i < n4; i += stride) p[i] = z;
}

__global__ __launch_bounds__(256)
void zero_int_kernel(int* __restrict__ p, int n) {
    int i = blockIdx.x * blockDim.x + threadIdx.x;
    int stride = gridDim.x * blockDim.x;
    for (; i < n; i += stride) p[i] = 0;
}

// ---------------------------------------------------------------- weight prep
__global__ __launch_bounds__(256)
void tr_kernel(const float* __restrict__ src, __bf16* __restrict__ dst, int nmat) {
    int idx = blockIdx.x * blockDim.x + threadIdx.x;
    int total = nmat * 16384;
    if (idx >= total) return;
    int m = idx >> 14;
    int col = (idx >> 7) & 127;
    int k = idx & 127;
    dst[idx] = (__bf16)src[m * 16384 + k * 128 + col];
}

// ---------------------------------------------------------------- CSR build
// all 3 hops' histograms in one pass, int4-vectorized
__global__ __launch_bounds__(256)
void hist3_kernel(const int* __restrict__ e1, const int* __restrict__ e2,
                  const int* __restrict__ e3, int* __restrict__ degs) {
    const int Q = NEDGE / 4;               // 2^20 int4 per list
    int j = blockIdx.x * blockDim.x + threadIdx.x;
    int stride = gridDim.x * blockDim.x;
    for (; j < 3 * Q; j += stride) {
        int hop = j >> 20;
        int idx = j & (Q - 1);
        const int* e = hop == 0 ? e1 : hop == 1 ? e2 : e3;
        int4 v = ((const int4*)e)[idx];
        int* d = degs + hop * N_NODES;
        atomicAdd(&d[v.x], 1); atomicAdd(&d[v.y], 1);
        atomicAdd(&d[v.z], 1); atomicAdd(&d[v.w], 1);
    }
}

// 3 blocks, one per hop; exclusive scan of deg -> offs, cursor; offs[N]=total
__global__ __launch_bounds__(1024)
void scan3_kernel(const int* __restrict__ degs, int* __restrict__ offs3,
                  int* __restrict__ curs) {
    __shared__ int part[1024];
    const int hop = blockIdx.x;
    const int* deg = degs + (size_t)hop * N_NODES;
    int* offs = offs3 + (size_t)hop * (N_NODES + 1);
    int* cursor = curs + (size_t)hop * N_NODES;
    const int t = threadIdx.x;
    const int base = t * (N_NODES / 1024);
    int s = 0;
    for (int i = 0; i < N_NODES / 1024; ++i) s += deg[base + i];
    part[t] = s;
    __syncthreads();
    for (int d = 1; d < 1024; d <<= 1) {
        int v = (t >= d) ? part[t - d] : 0;
        __syncthreads();
        part[t] += v;
        __syncthreads();
    }
    int run = (t == 0) ? 0 : part[t - 1];
    for (int i = 0; i < N_NODES / 1024; ++i) {
        int idx = base + i;
        int d = deg[idx];
        offs[idx] = run;
        cursor[idx] = run;
        run += d;
    }
    if (t == 1023) offs[N_NODES] = run;
}

// windowed scatter: pass p only writes dest rows [p*SC_WIN, (p+1)*SC_WIN)
// -> live col/cursor window ~2MB, L2-resident, kills write amplification
__global__ __launch_bounds__(256)
void scatter_kernel(const int* __restrict__ edges, int* __restrict__ cursor,
                    int* __restrict__ col) {
    const int Q = NEDGE / 4;
    const int tid0 = blockIdx.x * blockDim.x + threadIdx.x;
    const int stride = gridDim.x * blockDim.x;
    for (int pass = 0; pass < SC_PASS; ++pass) {
        const int lo = pass * SC_WIN;
        for (int j = tid0; j < Q; j += stride) {
            int4 r4 = ((const int4*)edges)[j];
#pragma unroll
            for (int k = 0; k < 4; ++k) {
                int r = (k == 0) ? r4.x : (k == 1) ? r4.y : (k == 2) ? r4.z : r4.w;
                if ((unsigned)(r - lo) < (unsigned)SC_WIN) {
                    int c = edges[NEDGE + j * 4 + k];
                    int p = atomicAdd(&cursor[r], 1);
                    col[p] = c;
                }
            }
        }
    }
}

// ---------------------------------------------------------------- CSR spmm (bf16)
__global__ __launch_bounds__(256)
void csr_spmm_kernel(const int* __restrict__ offs, const int* __restrict__ col,
                     const __bf16* __restrict__ xin, __bf16* __restrict__ outb) {
    const int lane = threadIdx.x & 63;
    const int row = blockIdx.x * (blockDim.x >> 6) + (threadIdx.x >> 6);
    if (row >= N_NODES) return;
    const int beg = offs[row];
    const int end = offs[row + 1];

    float a0 = 0.f, a1 = 0.f, b0 = 0.f, b1 = 0.f;
    float c0f = 0.f, c1f = 0.f, d0 = 0.f, d1 = 0.f;
    for (int b = beg; b < end; b += 64) {
        const int n = min(64, end - b);
        int cidx = (b + lane < end) ? col[b + lane] : 0;
        int i = 0;
        for (; i + 4 <= n; i += 4) {
            int e0 = __shfl(cidx, i);
            int e1 = __shfl(cidx, i + 1);
            int e2 = __shfl(cidx, i + 2);
            int e3 = __shfl(cidx, i + 3);
            unsigned v0 = *(const unsigned*)(xin + (size_t)e0 * 128 + lane * 2);
            unsigned v1 = *(const unsigned*)(xin + (size_t)e1 * 128 + lane * 2);
            unsigned v2 = *(const unsigned*)(xin + (size_t)e2 * 128 + lane * 2);
            unsigned v3 = *(const unsigned*)(xin + (size_t)e3 * 128 + lane * 2);
            a0 += __uint_as_float(v0 << 16); a1 += __uint_as_float(v0 & 0xffff0000u);
            b0 += __uint_as_float(v1 << 16); b1 += __uint_as_float(v1 & 0xffff0000u);
            c0f += __uint_as_float(v2 << 16); c1f += __uint_as_float(v2 & 0xffff0000u);
            d0 += __uint_as_float(v3 << 16); d1 += __uint_as_float(v3 & 0xffff0000u);
        }
        for (; i < n; ++i) {
            int e = __shfl(cidx, i);
            unsigned v = *(const unsigned*)(xin + (size_t)e * 128 + lane * 2);
            a0 += __uint_as_float(v << 16); a1 += __uint_as_float(v & 0xffff0000u);
        }
    }
    float o0 = a0 + b0 + c0f + d0;
    float o1 = a1 + b1 + c1f + d1;
    union { unsigned u; __bf16 h[2]; } pk;
    pk.h[0] = (__bf16)o0; pk.h[1] = (__bf16)o1;
    *(unsigned*)(outb + (size_t)row * 128 + lane * 2) = pk.u;
}

// ---------------------------------------------------------------- staging helpers
__device__ __forceinline__ void stage_bf16_tile(char* dst, const __bf16* src, int tid) {
#pragma unroll
    for (int it = 0; it < 8; ++it) {
        int c = tid + it * 256;
        int r = c >> 4, o = c & 15;
        uint4 v = *(const uint4*)(src + (size_t)r * 128 + o * 8);
        *(uint4*)(dst + lds_off(r, o * 16)) = v;
    }
}

__device__ __forceinline__ void stage_f32_tile(char* dst, const float* src, int tid) {
#pragma unroll
    for (int it = 0; it < 16; ++it) {
        int c = tid + it * 256;
        int r = c >> 5, o = c & 31;
        floatx4 v = *(const floatx4*)(src + (size_t)r * 128 + o * 4);
        bf16x4 h;
        h[0] = (__bf16)v[0]; h[1] = (__bf16)v[1];
        h[2] = (__bf16)v[2]; h[3] = (__bf16)v[3];
        *(bf16x4*)(dst + lds_off(r, o * 8)) = h;
    }
}

__device__ __forceinline__ void mfma_phase(const char* az, const char* wb,
                                           int r0, int lrow, int grp,
                                           f32x4 (&acc)[2][8]) {
    bf16x8 am[2][4];
#pragma unroll
    for (int mt = 0; mt < 2; ++mt)
#pragma unroll
        for (int kk = 0; kk < 4; ++kk)
            am[mt][kk] = *(const bf16x8*)(az + lds_off(r0 + mt * 16 + lrow,
                                                       kk * 64 + grp * 16));
#pragma unroll
    for (int kk = 0; kk < 4; ++kk)
#pragma unroll
        for (int n = 0; n < 8; ++n) {
            bf16x8 b = *(const bf16x8*)(wb + lds_off(n * 16 + lrow,
                                                     kk * 64 + grp * 16));
#pragma unroll
            for (int mt = 0; mt < 2; ++mt)
                acc[mt][n] = __builtin_amdgcn_mfma_f32_16x16x32_bf16(
                    am[mt][kk], b, acc[mt][n], 0, 0, 0);
        }
}

// ---------------------------------------------------------------- layer 1 (MFMA)
__global__ __launch_bounds__(256, 2)
void layer1_kernel(const float* __restrict__ x, const float* __restrict__ rw,
                   const float* __restrict__ f1, const float* __restrict__ f2,
                   const float* __restrict__ f3,
                   const __bf16* __restrict__ wt1, const float* __restrict__ b1,
                   const __bf16* __restrict__ wt2, const float* __restrict__ b2,
                   __bf16* __restrict__ x1out)
{
    __shared__ uint4 lds_u4[4096];
    char* AZ = (char*)lds_u4;
    char* WB = (char*)lds_u4 + 32768;
    const int tid = threadIdx.x;
    const int lane = tid & 63;
    const int w = tid >> 6;
    const int r0 = w * 32;
    const int lrow = lane & 15;
    const int grp = lane >> 4;
    const int row0 = blockIdx.x * 128;

    f32x4 Y[2][8];
#pragma unroll
    for (int mt = 0; mt < 2; ++mt)
#pragma unroll
        for (int n = 0; n < 8; ++n) Y[mt][n] = {0.f, 0.f, 0.f, 0.f};

    for (int h = 0; h < 4; ++h) {
        __syncthreads();
        if (h == 0) {
#pragma unroll
            for (int it = 0; it < 16; ++it) {
                int c = tid + it * 256;
                int r = c >> 5, o = c & 31;
                const float* src = (o < 16)
                    ? (x  + (size_t)(row0 + r) * 64 + o * 4)
                    : (rw + (size_t)(row0 + r) * 64 + (o - 16) * 4);
                floatx4 v = *(const floatx4*)src;
                bf16x4 hh;
                hh[0] = (__bf16)v[0]; hh[1] = (__bf16)v[1];
                hh[2] = (__bf16)v[2]; hh[3] = (__bf16)v[3];
                *(bf16x4*)(AZ + lds_off(r, o * 8)) = hh;
            }
        } else {
            const float* feat = (h == 1) ? f1 : (h == 2) ? f2 : f3;
            stage_f32_tile(AZ, feat + (size_t)row0 * 128, tid);
        }
        stage_bf16_tile(WB, wt1 + (size_t)h * 16384, tid);
        __syncthreads();

        f32x4 acc1[2][8];
#pragma unroll
        for (int mt = 0; mt < 2; ++mt)
#pragma unroll
            for (int n = 0; n < 8; ++n) acc1[mt][n] = {0.f, 0.f, 0.f, 0.f};
        mfma_phase(AZ, WB, r0, lrow, grp, acc1);

#pragma unroll
        for (int n = 0; n < 8; ++n) {
            float bias = b1[h * 128 + n * 16 + lrow];
#pragma unroll
            for (int mt = 0; mt < 2; ++mt)
#pragma unroll
                for (int rg = 0; rg < 4; ++rg) {
                    float v = fmaxf(acc1[mt][n][rg] + bias, 0.f);
                    int zr = r0 + mt * 16 + grp * 4 + rg;
                    *(__bf16*)(AZ + lds_off(zr, (n * 16 + lrow) * 2)) = (__bf16)v;
                }
        }
        __syncthreads();
        stage_bf16_tile(WB, wt2 + (size_t)h * 16384, tid);
        __syncthreads();
        mfma_phase(AZ, WB, r0, lrow, grp, Y);
    }

#pragma unroll
    for (int n = 0; n < 8; ++n) {
        int cc = n * 16 + lrow;
        float bs = b2[cc] + b2[128 + cc] + b2[256 + cc] + b2[384 + cc];
#pragma unroll
        for (int mt = 0; mt < 2; ++mt)
#pragma unroll
            for (int rg = 0; rg < 4; ++rg) {
                int gr = row0 + r0 + mt * 16 + grp * 4 + rg;
                x1out[(size_t)gr * 128 + cc] = (__bf16)(Y[mt][n][rg] + bs);
            }
    }
}

// ---------------------------------------------------------------- layer 2 + lin + pool (MFMA)
__global__ __launch_bounds__(256, 2)
void layer2_kernel(const __bf16* __restrict__ x1b, const __bf16* __restrict__ s1,
                   const __bf16* __restrict__ s2, const __bf16* __restrict__ s3,
                   const __bf16* __restrict__ wt1, const float* __restrict__ b1,
                   const __bf16* __restrict__ wt2, const float* __restrict__ b2,
                   const __bf16* __restrict__ wtl, const float* __restrict__ linb,
                   const int* __restrict__ batch, float* __restrict__ dout)
{
    __shared__ uint4 lds_u4[4096];
    char* AZ = (char*)lds_u4;
    char* WB = (char*)lds_u4 + 32768;
    const int tid = threadIdx.x;
    const int lane = tid & 63;
    const int w = tid >> 6;
    const int r0 = w * 32;
    const int lrow = lane & 15;
    const int grp = lane >> 4;
    const int row0 = blockIdx.x * 128;

    f32x4 Y[2][8];
#pragma unroll
    for (int mt = 0; mt < 2; ++mt)
#pragma unroll
        for (int n = 0; n < 8; ++n) Y[mt][n] = {0.f, 0.f, 0.f, 0.f};

    for (int h = 0; h < 4; ++h) {
        const __bf16* feat = (h == 0) ? x1b : (h == 1) ? s1 : (h == 2) ? s2 : s3;
        __syncthreads();
        stage_bf16_tile(AZ, feat + (size_t)row0 * 128, tid);
        stage_bf16_tile(WB, wt1 + (size_t)h * 16384, tid);
        __syncthreads();

        f32x4 acc1[2][8];
#pragma unroll
        for (int mt = 0; mt < 2; ++mt)
#pragma unroll
            for (int n = 0; n < 8; ++n) acc1[mt][n] = {0.f, 0.f, 0.f, 0.f};
        mfma_phase(AZ, WB, r0, lrow, grp, acc1);

#pragma unroll
        for (int n = 0; n < 8; ++n) {
            float bias = b1[h * 128 + n * 16 + lrow];
#pragma unroll
            for (int mt = 0; mt < 2; ++mt)
#pragma unroll
                for (int rg = 0; rg < 4; ++rg) {
                    float v = fmaxf(acc1[mt][n][rg] + bias, 0.f);
                    int zr = r0 + mt * 16 + grp * 4 + rg;
                    *(__bf16*)(AZ + lds_off(zr, (n * 16 + lrow) * 2)) = (__bf16)v;
                }
        }
        __syncthreads();
        stage_bf16_tile(WB, wt2 + (size_t)h * 16384, tid);
        __syncthreads();
        mfma_phase(AZ, WB, r0, lrow, grp, Y);
    }

#pragma unroll
    for (int n = 0; n < 8; ++n) {
        int cc = n * 16 + lrow;
        float bs = b2[cc] + b2[128 + cc] + b2[256 + cc] + b2[384 + cc];
#pragma unroll
        for (int mt = 0; mt < 2; ++mt)
#pragma unroll
            for (int rg = 0; rg < 4; ++rg) {
                float v = Y[mt][n][rg] + bs;
                int zr = r0 + mt * 16 + grp * 4 + rg;
                *(__bf16*)(AZ + lds_off(zr, (n * 16 + lrow) * 2)) = (__bf16)v;
            }
    }
    __syncthreads();
    stage_bf16_tile(WB, wtl + 16384, tid);
    __syncthreads();

    f32x4 o[2][8];
#pragma unroll
    for (int mt = 0; mt < 2; ++mt)
#pragma unroll
        for (int n = 0; n < 8; ++n) o[mt][n] = {0.f, 0.f, 0.f, 0.f};
    mfma_phase(AZ, WB, r0, lrow, grp, o);

    __syncthreads();
    stage_bf16_tile(AZ, x1b + (size_t)row0 * 128, tid);
    stage_bf16_tile(WB, wtl, tid);
    __syncthreads();
    mfma_phase(AZ, WB, r0, lrow, grp, o);

    __syncthreads();
    float* tile32 = (float*)lds_u4;
#pragma unroll
    for (int n = 0; n < 8; ++n) {
        int cc = n * 16 + lrow;
        float lb = linb[cc];
#pragma unroll
        for (int mt = 0; mt < 2; ++mt)
#pragma unroll
            for (int rg = 0; rg < 4; ++rg) {
                int rl = r0 + mt * 16 + grp * 4 + rg;
                tile32[rl * 128 + cc] = o[mt][n][rg] + lb;
            }
    }
    __syncthreads();

    if (tid < 128) {
        const int d = tid;
        float acc = 0.f;
        int cur = batch[row0];
        for (int r = 0; r < 128; ++r) {
            int b = batch[row0 + r];
            if (b != cur) {
                atomicAdd(dout + (size_t)cur * 128 + d, acc);
                acc = 0.f;
                cur = b;
            }
            acc += tile32[r * 128 + d];
        }
        atomicAdd(dout + (size_t)cur * 128 + d, acc);
    }
}

// ---------------------------------------------------------------- launch
extern "C" void kernel_launch(void* const* d_in, const int* in_sizes, int n_in,
                              void* d_out, int out_size, void* d_ws, size_t ws_size,
                              hipStream_t stream) {
    (void)in_sizes; (void)n_in; (void)out_size; (void)ws_size;

    const float* x    = (const float*)d_in[0];
    const float* rw   = (const float*)d_in[1];
    const float* f1   = (const float*)d_in[2];
    const float* f2   = (const float*)d_in[3];
    const float* f3   = (const float*)d_in[4];
    const int*   e1   = (const int*)d_in[5];
    const int*   e2   = (const int*)d_in[6];
    const int*   e3   = (const int*)d_in[7];
    const int*   batch= (const int*)d_in[8];
    const float* l1w1 = (const float*)d_in[9];
    const float* l1b1 = (const float*)d_in[10];
    const float* l1w2 = (const float*)d_in[11];
    const float* l1b2 = (const float*)d_in[12];
    const float* l2w1 = (const float*)d_in[13];
    const float* l2b1 = (const float*)d_in[14];
    const float* l2w2 = (const float*)d_in[15];
    const float* l2b2 = (const float*)d_in[16];
    const float* linw = (const float*)d_in[17];
    const float* linb = (const float*)d_in[18];

    float* out = (float*)d_out;

    // workspace layout
    __bf16* x1b = (__bf16*)d_ws;
    __bf16* s1b = x1b + (size_t)N_NODES * 128;
    __bf16* s2b = s1b + (size_t)N_NODES * 128;
    __bf16* s3b = s2b + (size_t)N_NODES * 128;
    __bf16* wt  = s3b + (size_t)N_NODES * 128;
    __bf16* wt_l1w1 = wt;
    __bf16* wt_l1w2 = wt + 4 * 16384;
    __bf16* wt_l2w1 = wt + 8 * 16384;
    __bf16* wt_l2w2 = wt + 12 * 16384;
    __bf16* wt_lin  = wt + 16 * 16384;
    int* ibase = (int*)(wt + 18 * 16384);
    int* degs  = ibase;                                   // 3*N
    int* offs3 = degs + (size_t)3 * N_NODES;              // 3*(N+1)
    int* curs  = offs3 + (size_t)3 * (N_NODES + 1);       // 3*N
    int* cols  = curs + (size_t)3 * N_NODES;              // 3*NEDGE

    tr_kernel<<<256, 256, 0, stream>>>(l1w1, wt_l1w1, 4);
    tr_kernel<<<256, 256, 0, stream>>>(l1w2, wt_l1w2, 4);
    tr_kernel<<<256, 256, 0, stream>>>(l2w1, wt_l2w1, 4);
    tr_kernel<<<256, 256, 0, stream>>>(l2w2, wt_l2w2, 4);
    tr_kernel<<<128, 256, 0, stream>>>(linw, wt_lin, 2);

    zero_kernel<<<64, 256, 0, stream>>>((floatx4*)out, (long)NGRAPH * 32);
    zero_int_kernel<<<384, 256, 0, stream>>>(degs, 3 * N_NODES);

    layer1_kernel<<<N_NODES / 128, 256, 0, stream>>>(
        x, rw, f1, f2, f3, wt_l1w1, l1b1, wt_l1w2, l1b2, x1b);

    hist3_kernel<<<8192, 256, 0, stream>>>(e1, e2, e3, degs);
    scan3_kernel<<<3, 1024, 0, stream>>>(degs, offs3, curs);

    const int* es[3] = {e1, e2, e3};
    __bf16* ss[3] = {s1b, s2b, s3b};
    for (int hop = 0; hop < 3; ++hop) {
        scatter_kernel<<<4096, 256, 0, stream>>>(
            es[hop], curs + (size_t)hop * N_NODES, cols + (size_t)hop * NEDGE);
        csr_spmm_kernel<<<N_NODES / 4, 256, 0, stream>>>(
            offs3 + (size_t)hop * (N_NODES + 1), cols + (size_t)hop * NEDGE,
            x1b, ss[hop]);
    }

    layer2_kernel<<<N_NODES / 128, 256, 0, stream>>>(
        x1b, s1b, s2b, s3b, wt_l2w1, l2b1, wt_l2w2, l2b2, wt_lin, linb, batch, out);
}

// Round 5
// 1542.513 us; speedup vs baseline: 7.4730x; 1.2772x over previous
//
#include <hip/hip_runtime.h>

#define N_NODES 131072
#define DIM     128
#define NGRAPH  1024
#define NEDGE   4194304

#define W_BINS  16384                 // bins per window (64 KiB LDS)
#define N_WIN   (N_NODES / W_BINS)    // 8 windows
#define B_BLK   16                    // blocks (slices) per window
#define SLICE   (NEDGE / B_BLK)       // 262144 edges per slice

typedef float floatx4 __attribute__((ext_vector_type(4)));
typedef float f32x4  __attribute__((ext_vector_type(4)));
typedef __bf16 bf16x8 __attribute__((ext_vector_type(8)));
typedef __bf16 bf16x4 __attribute__((ext_vector_type(4)));

// swizzled LDS byte offset for a [rows][128] bf16 tile (row stride 256 B)
__device__ __forceinline__ int lds_off(int row, int kb) {
    return row * 256 + (kb ^ ((row & 7) << 4));
}

// ---------------------------------------------------------------- zero
__global__ __launch_bounds__(256)
void zero_kernel(floatx4* __restrict__ p, long n4) {
    long i = (long)blockIdx.x * blockDim.x + threadIdx.x;
    long stride = (long)gridDim.x * blockDim.x;
    floatx4 z = {0.f, 0.f, 0.f, 0.f};
    for (; i < n4; i += stride) p[i] = z;
}

// ---------------------------------------------------------------- weight prep
__global__ __launch_bounds__(256)
void tr_kernel(const float* __restrict__ src, __bf16* __restrict__ dst, int nmat) {
    int idx = blockIdx.x * blockDim.x + threadIdx.x;
    int total = nmat * 16384;
    if (idx >= total) return;
    int m = idx >> 14;
    int col = (idx >> 7) & 127;
    int k = idx & 127;
    dst[idx] = (__bf16)src[m * 16384 + k * 128 + col];
}

// ---------------------------------------------------------------- CSR build (atomic-free)
// pass A: per-(hop,window,block) LDS histogram -> blockhist (streaming write)
__global__ __launch_bounds__(256)
void part_hist_kernel(const int* __restrict__ e1, const int* __restrict__ e2,
                      const int* __restrict__ e3, int* __restrict__ blockhist) {
    const int gb  = blockIdx.x;
    const int b   = gb % B_BLK;
    const int w   = (gb / B_BLK) % N_WIN;
    const int hop = gb / (B_BLK * N_WIN);
    const int* rows = hop == 0 ? e1 : hop == 1 ? e2 : e3;

    __shared__ int h[W_BINS];
    for (int i = threadIdx.x; i < W_BINS; i += 256) h[i] = 0;
    __syncthreads();

    const int lo = w * W_BINS;
    const int4* src = (const int4*)rows + (size_t)b * (SLICE / 4);
    for (int j = threadIdx.x; j < SLICE / 4; j += 256) {
        int4 v = src[j];
        if ((unsigned)(v.x - lo) < (unsigned)W_BINS) atomicAdd(&h[v.x - lo], 1);
        if ((unsigned)(v.y - lo) < (unsigned)W_BINS) atomicAdd(&h[v.y - lo], 1);
        if ((unsigned)(v.z - lo) < (unsigned)W_BINS) atomicAdd(&h[v.z - lo], 1);
        if ((unsigned)(v.w - lo) < (unsigned)W_BINS) atomicAdd(&h[v.w - lo], 1);
    }
    __syncthreads();

    int* dst = blockhist + (((size_t)hop * N_WIN + w) * B_BLK + b) * W_BINS;
    for (int i = threadIdx.x; i < W_BINS; i += 256) dst[i] = h[i];
}

// per-(hop,bin): deg = sum over blocks; blockhist -> in-place exclusive prefix over b
__global__ __launch_bounds__(256)
void colscan_kernel(int* __restrict__ blockhist, int* __restrict__ degs) {
    int t = blockIdx.x * 256 + threadIdx.x;
    if (t >= 3 * N_NODES) return;
    int hop = t / N_NODES;
    int bin = t % N_NODES;
    int w = bin / W_BINS, i = bin % W_BINS;
    int* p = blockhist + (((size_t)hop * N_WIN + w) * B_BLK) * W_BINS + i;
    int run = 0;
#pragma unroll
    for (int b = 0; b < B_BLK; ++b) {
        int v = p[(size_t)b * W_BINS];
        p[(size_t)b * W_BINS] = run;
        run += v;
    }
    degs[t] = run;
}

// 3 blocks, one per hop; exclusive scan of deg -> offs; offs[N]=total
__global__ __launch_bounds__(1024)
void scan3_kernel(const int* __restrict__ degs, int* __restrict__ offs3) {
    __shared__ int part[1024];
    const int hop = blockIdx.x;
    const int* deg = degs + (size_t)hop * N_NODES;
    int* offs = offs3 + (size_t)hop * (N_NODES + 1);
    const int t = threadIdx.x;
    const int base = t * (N_NODES / 1024);
    int s = 0;
    for (int i = 0; i < N_NODES / 1024; ++i) s += deg[base + i];
    part[t] = s;
    __syncthreads();
    for (int d = 1; d < 1024; d <<= 1) {
        int v = (t >= d) ? part[t - d] : 0;
        __syncthreads();
        part[t] += v;
        __syncthreads();
    }
    int run = (t == 0) ? 0 : part[t - 1];
    for (int i = 0; i < N_NODES / 1024; ++i) {
        int idx = base + i;
        int d = deg[idx];
        offs[idx] = run;
        run += d;
    }
    if (t == 1023) offs[N_NODES] = run;
}

// pass B: scatter with LDS cursors (zero global atomics; disjoint ranges per block)
__global__ __launch_bounds__(256)
void scatter_ns_kernel(const int* __restrict__ e1, const int* __restrict__ e2,
                       const int* __restrict__ e3, const int* __restrict__ offs3,
                       const int* __restrict__ blockhist, int* __restrict__ cols) {
    const int gb  = blockIdx.x;
    const int b   = gb % B_BLK;
    const int w   = (gb / B_BLK) % N_WIN;
    const int hop = gb / (B_BLK * N_WIN);
    const int* rows = hop == 0 ? e1 : hop == 1 ? e2 : e3;
    const int* csrc = rows + NEDGE;
    int* col = cols + (size_t)hop * NEDGE;

    __shared__ int cur[W_BINS];
    const int lo = w * W_BINS;
    const int* base = blockhist + (((size_t)hop * N_WIN + w) * B_BLK + b) * W_BINS;
    const int* offs = offs3 + (size_t)hop * (N_NODES + 1) + lo;
    for (int i = threadIdx.x; i < W_BINS; i += 256) cur[i] = offs[i] + base[i];
    __syncthreads();

    const int4* r4 = (const int4*)rows + (size_t)b * (SLICE / 4);
    const int4* c4 = (const int4*)csrc + (size_t)b * (SLICE / 4);
    for (int j = threadIdx.x; j < SLICE / 4; j += 256) {
        int4 r = r4[j];
        int4 c = c4[j];
        if ((unsigned)(r.x - lo) < (unsigned)W_BINS) { int p = atomicAdd(&cur[r.x - lo], 1); col[p] = c.x; }
        if ((unsigned)(r.y - lo) < (unsigned)W_BINS) { int p = atomicAdd(&cur[r.y - lo], 1); col[p] = c.y; }
        if ((unsigned)(r.z - lo) < (unsigned)W_BINS) { int p = atomicAdd(&cur[r.z - lo], 1); col[p] = c.z; }
        if ((unsigned)(r.w - lo) < (unsigned)W_BINS) { int p = atomicAdd(&cur[r.w - lo], 1); col[p] = c.w; }
    }
}

// ---------------------------------------------------------------- CSR spmm (bf16)
__global__ __launch_bounds__(256)
void csr_spmm_kernel(const int* __restrict__ offs, const int* __restrict__ col,
                     const __bf16* __restrict__ xin, __bf16* __restrict__ outb) {
    const int lane = threadIdx.x & 63;
    const int row = blockIdx.x * (blockDim.x >> 6) + (threadIdx.x >> 6);
    if (row >= N_NODES) return;
    const int beg = offs[row];
    const int end = offs[row + 1];

    float a0 = 0.f, a1 = 0.f, b0 = 0.f, b1 = 0.f;
    float c0f = 0.f, c1f = 0.f, d0 = 0.f, d1 = 0.f;
    for (int b = beg; b < end; b += 64) {
        const int n = min(64, end - b);
        int cidx = (b + lane < end) ? col[b + lane] : 0;
        int i = 0;
        for (; i + 4 <= n; i += 4) {
            int e0 = __shfl(cidx, i);
            int e1 = __shfl(cidx, i + 1);
            int e2 = __shfl(cidx, i + 2);
            int e3 = __shfl(cidx, i + 3);
            unsigned v0 = *(const unsigned*)(xin + (size_t)e0 * 128 + lane * 2);
            unsigned v1 = *(const unsigned*)(xin + (size_t)e1 * 128 + lane * 2);
            unsigned v2 = *(const unsigned*)(xin + (size_t)e2 * 128 + lane * 2);
            unsigned v3 = *(const unsigned*)(xin + (size_t)e3 * 128 + lane * 2);
            a0 += __uint_as_float(v0 << 16); a1 += __uint_as_float(v0 & 0xffff0000u);
            b0 += __uint_as_float(v1 << 16); b1 += __uint_as_float(v1 & 0xffff0000u);
            c0f += __uint_as_float(v2 << 16); c1f += __uint_as_float(v2 & 0xffff0000u);
            d0 += __uint_as_float(v3 << 16); d1 += __uint_as_float(v3 & 0xffff0000u);
        }
        for (; i < n; ++i) {
            int e = __shfl(cidx, i);
            unsigned v = *(const unsigned*)(xin + (size_t)e * 128 + lane * 2);
            a0 += __uint_as_float(v << 16); a1 += __uint_as_float(v & 0xffff0000u);
        }
    }
    float o0 = a0 + b0 + c0f + d0;
    float o1 = a1 + b1 + c1f + d1;
    union { unsigned u; __bf16 h[2]; } pk;
    pk.h[0] = (__bf16)o0; pk.h[1] = (__bf16)o1;
    *(unsigned*)(outb + (size_t)row * 128 + lane * 2) = pk.u;
}

// ---------------------------------------------------------------- staging helpers
__device__ __forceinline__ void stage_bf16_tile(char* dst, const __bf16* src, int tid) {
#pragma unroll
    for (int it = 0; it < 8; ++it) {
        int c = tid + it * 256;
        int r = c >> 4, o = c & 15;
        uint4 v = *(const uint4*)(src + (size_t)r * 128 + o * 8);
        *(uint4*)(dst + lds_off(r, o * 16)) = v;
    }
}

__device__ __forceinline__ void stage_f32_tile(char* dst, const float* src, int tid) {
#pragma unroll
    for (int it = 0; it < 16; ++it) {
        int c = tid + it * 256;
        int r = c >> 5, o = c & 31;
        floatx4 v = *(const floatx4*)(src + (size_t)r * 128 + o * 4);
        bf16x4 h;
        h[0] = (__bf16)v[0]; h[1] = (__bf16)v[1];
        h[2] = (__bf16)v[2]; h[3] = (__bf16)v[3];
        *(bf16x4*)(dst + lds_off(r, o * 8)) = h;
    }
}

__device__ __forceinline__ void mfma_phase(const char* az, const char* wb,
                                           int r0, int lrow, int grp,
                                           f32x4 (&acc)[2][8]) {
    bf16x8 am[2][4];
#pragma unroll
    for (int mt = 0; mt < 2; ++mt)
#pragma unroll
        for (int kk = 0; kk < 4; ++kk)
            am[mt][kk] = *(const bf16x8*)(az + lds_off(r0 + mt * 16 + lrow,
                                                       kk * 64 + grp * 16));
#pragma unroll
    for (int kk = 0; kk < 4; ++kk)
#pragma unroll
        for (int n = 0; n < 8; ++n) {
            bf16x8 b = *(const bf16x8*)(wb + lds_off(n * 16 + lrow,
                                                     kk * 64 + grp * 16));
#pragma unroll
            for (int mt = 0; mt < 2; ++mt)
                acc[mt][n] = __builtin_amdgcn_mfma_f32_16x16x32_bf16(
                    am[mt][kk], b, acc[mt][n], 0, 0, 0);
        }
}

// ---------------------------------------------------------------- layer 1 (MFMA)
__global__ __launch_bounds__(256, 2)
void layer1_kernel(const float* __restrict__ x, const float* __restrict__ rw,
                   const float* __restrict__ f1, const float* __restrict__ f2,
                   const float* __restrict__ f3,
                   const __bf16* __restrict__ wt1, const float* __restrict__ b1,
                   const __bf16* __restrict__ wt2, const float* __restrict__ b2,
                   __bf16* __restrict__ x1out)
{
    __shared__ uint4 lds_u4[4096];
    char* AZ = (char*)lds_u4;
    char* WB = (char*)lds_u4 + 32768;
    const int tid = threadIdx.x;
    const int lane = tid & 63;
    const int w = tid >> 6;
    const int r0 = w * 32;
    const int lrow = lane & 15;
    const int grp = lane >> 4;
    const int row0 = blockIdx.x * 128;

    f32x4 Y[2][8];
#pragma unroll
    for (int mt = 0; mt < 2; ++mt)
#pragma unroll
        for (int n = 0; n < 8; ++n) Y[mt][n] = {0.f, 0.f, 0.f, 0.f};

    for (int h = 0; h < 4; ++h) {
        __syncthreads();
        if (h == 0) {
#pragma unroll
            for (int it = 0; it < 16; ++it) {
                int c = tid + it * 256;
                int r = c >> 5, o = c & 31;
                const float* src = (o < 16)
                    ? (x  + (size_t)(row0 + r) * 64 + o * 4)
                    : (rw + (size_t)(row0 + r) * 64 + (o - 16) * 4);
                floatx4 v = *(const floatx4*)src;
                bf16x4 hh;
                hh[0] = (__bf16)v[0]; hh[1] = (__bf16)v[1];
                hh[2] = (__bf16)v[2]; hh[3] = (__bf16)v[3];
                *(bf16x4*)(AZ + lds_off(r, o * 8)) = hh;
            }
        } else {
            const float* feat = (h == 1) ? f1 : (h == 2) ? f2 : f3;
            stage_f32_tile(AZ, feat + (size_t)row0 * 128, tid);
        }
        stage_bf16_tile(WB, wt1 + (size_t)h * 16384, tid);
        __syncthreads();

        f32x4 acc1[2][8];
#pragma unroll
        for (int mt = 0; mt < 2; ++mt)
#pragma unroll
            for (int n = 0; n < 8; ++n) acc1[mt][n] = {0.f, 0.f, 0.f, 0.f};
        mfma_phase(AZ, WB, r0, lrow, grp, acc1);

#pragma unroll
        for (int n = 0; n < 8; ++n) {
            float bias = b1[h * 128 + n * 16 + lrow];
#pragma unroll
            for (int mt = 0; mt < 2; ++mt)
#pragma unroll
                for (int rg = 0; rg < 4; ++rg) {
                    float v = fmaxf(acc1[mt][n][rg] + bias, 0.f);
                    int zr = r0 + mt * 16 + grp * 4 + rg;
                    *(__bf16*)(AZ + lds_off(zr, (n * 16 + lrow) * 2)) = (__bf16)v;
                }
        }
        __syncthreads();
        stage_bf16_tile(WB, wt2 + (size_t)h * 16384, tid);
        __syncthreads();
        mfma_phase(AZ, WB, r0, lrow, grp, Y);
    }

#pragma unroll
    for (int n = 0; n < 8; ++n) {
        int cc = n * 16 + lrow;
        float bs = b2[cc] + b2[128 + cc] + b2[256 + cc] + b2[384 + cc];
#pragma unroll
        for (int mt = 0; mt < 2; ++mt)
#pragma unroll
            for (int rg = 0; rg < 4; ++rg) {
                int gr = row0 + r0 + mt * 16 + grp * 4 + rg;
                x1out[(size_t)gr * 128 + cc] = (__bf16)(Y[mt][n][rg] + bs);
            }
    }
}

// ---------------------------------------------------------------- layer 2 + lin + pool (MFMA)
__global__ __launch_bounds__(256, 2)
void layer2_kernel(const __bf16* __restrict__ x1b, const __bf16* __restrict__ s1,
                   const __bf16* __restrict__ s2, const __bf16* __restrict__ s3,
                   const __bf16* __restrict__ wt1, const float* __restrict__ b1,
                   const __bf16* __restrict__ wt2, const float* __restrict__ b2,
                   const __bf16* __restrict__ wtl, const float* __restrict__ linb,
                   const int* __restrict__ batch, float* __restrict__ dout)
{
    __shared__ uint4 lds_u4[4096];
    char* AZ = (char*)lds_u4;
    char* WB = (char*)lds_u4 + 32768;
    const int tid = threadIdx.x;
    const int lane = tid & 63;
    const int w = tid >> 6;
    const int r0 = w * 32;
    const int lrow = lane & 15;
    const int grp = lane >> 4;
    const int row0 = blockIdx.x * 128;

    f32x4 Y[2][8];
#pragma unroll
    for (int mt = 0; mt < 2; ++mt)
#pragma unroll
        for (int n = 0; n < 8; ++n) Y[mt][n] = {0.f, 0.f, 0.f, 0.f};

    for (int h = 0; h < 4; ++h) {
        const __bf16* feat = (h == 0) ? x1b : (h == 1) ? s1 : (h == 2) ? s2 : s3;
        __syncthreads();
        stage_bf16_tile(AZ, feat + (size_t)row0 * 128, tid);
        stage_bf16_tile(WB, wt1 + (size_t)h * 16384, tid);
        __syncthreads();

        f32x4 acc1[2][8];
#pragma unroll
        for (int mt = 0; mt < 2; ++mt)
#pragma unroll
            for (int n = 0; n < 8; ++n) acc1[mt][n] = {0.f, 0.f, 0.f, 0.f};
        mfma_phase(AZ, WB, r0, lrow, grp, acc1);

#pragma unroll
        for (int n = 0; n < 8; ++n) {
            float bias = b1[h * 128 + n * 16 + lrow];
#pragma unroll
            for (int mt = 0; mt < 2; ++mt)
#pragma unroll
                for (int rg = 0; rg < 4; ++rg) {
                    float v = fmaxf(acc1[mt][n][rg] + bias, 0.f);
                    int zr = r0 + mt * 16 + grp * 4 + rg;
                    *(__bf16*)(AZ + lds_off(zr, (n * 16 + lrow) * 2)) = (__bf16)v;
                }
        }
        __syncthreads();
        stage_bf16_tile(WB, wt2 + (size_t)h * 16384, tid);
        __syncthreads();
        mfma_phase(AZ, WB, r0, lrow, grp, Y);
    }

#pragma unroll
    for (int n = 0; n < 8; ++n) {
        int cc = n * 16 + lrow;
        float bs = b2[cc] + b2[128 + cc] + b2[256 + cc] + b2[384 + cc];
#pragma unroll
        for (int mt = 0; mt < 2; ++mt)
#pragma unroll
            for (int rg = 0; rg < 4; ++rg) {
                float v = Y[mt][n][rg] + bs;
                int zr = r0 + mt * 16 + grp * 4 + rg;
                *(__bf16*)(AZ + lds_off(zr, (n * 16 + lrow) * 2)) = (__bf16)v;
            }
    }
    __syncthreads();
    stage_bf16_tile(WB, wtl + 16384, tid);
    __syncthreads();

    f32x4 o[2][8];
#pragma unroll
    for (int mt = 0; mt < 2; ++mt)
#pragma unroll
        for (int n = 0; n < 8; ++n) o[mt][n] = {0.f, 0.f, 0.f, 0.f};
    mfma_phase(AZ, WB, r0, lrow, grp, o);

    __syncthreads();
    stage_bf16_tile(AZ, x1b + (size_t)row0 * 128, tid);
    stage_bf16_tile(WB, wtl, tid);
    __syncthreads();
    mfma_phase(AZ, WB, r0, lrow, grp, o);

    __syncthreads();
    float* tile32 = (float*)lds_u4;
#pragma unroll
    for (int n = 0; n < 8; ++n) {
        int cc = n * 16 + lrow;
        float lb = linb[cc];
#pragma unroll
        for (int mt = 0; mt < 2; ++mt)
#pragma unroll
            for (int rg = 0; rg < 4; ++rg) {
                int rl = r0 + mt * 16 + grp * 4 + rg;
                tile32[rl * 128 + cc] = o[mt][n][rg] + lb;
            }
    }
    __syncthreads();

    if (tid < 128) {
        const int d = tid;
        float acc = 0.f;
        int cur = batch[row0];
        for (int r = 0; r < 128; ++r) {
            int b = batch[row0 + r];
            if (b != cur) {
                atomicAdd(dout + (size_t)cur * 128 + d, acc);
                acc = 0.f;
                cur = b;
            }
            acc += tile32[r * 128 + d];
        }
        atomicAdd(dout + (size_t)cur * 128 + d, acc);
    }
}

// ---------------------------------------------------------------- launch
extern "C" void kernel_launch(void* const* d_in, const int* in_sizes, int n_in,
                              void* d_out, int out_size, void* d_ws, size_t ws_size,
                              hipStream_t stream) {
    (void)in_sizes; (void)n_in; (void)out_size; (void)ws_size;

    const float* x    = (const float*)d_in[0];
    const float* rw   = (const float*)d_in[1];
    const float* f1   = (const float*)d_in[2];
    const float* f2   = (const float*)d_in[3];
    const float* f3   = (const float*)d_in[4];
    const int*   e1   = (const int*)d_in[5];
    const int*   e2   = (const int*)d_in[6];
    const int*   e3   = (const int*)d_in[7];
    const int*   batch= (const int*)d_in[8];
    const float* l1w1 = (const float*)d_in[9];
    const float* l1b1 = (const float*)d_in[10];
    const float* l1w2 = (const float*)d_in[11];
    const float* l1b2 = (const float*)d_in[12];
    const float* l2w1 = (const float*)d_in[13];
    const float* l2b1 = (const float*)d_in[14];
    const float* l2w2 = (const float*)d_in[15];
    const float* l2b2 = (const float*)d_in[16];
    const float* linw = (const float*)d_in[17];
    const float* linb = (const float*)d_in[18];

    float* out = (float*)d_out;

    // workspace layout
    __bf16* x1b = (__bf16*)d_ws;
    __bf16* s1b = x1b + (size_t)N_NODES * 128;
    __bf16* s2b = s1b + (size_t)N_NODES * 128;
    __bf16* s3b = s2b + (size_t)N_NODES * 128;
    __bf16* wt  = s3b + (size_t)N_NODES * 128;
    __bf16* wt_l1w1 = wt;
    __bf16* wt_l1w2 = wt + 4 * 16384;
    __bf16* wt_l2w1 = wt + 8 * 16384;
    __bf16* wt_l2w2 = wt + 12 * 16384;
    __bf16* wt_lin  = wt + 16 * 16384;
    int* ibase = (int*)(wt + 18 * 16384);
    int* degs      = ibase;                                      // 3*N
    int* offs3     = degs + (size_t)3 * N_NODES;                 // 3*(N+1)
    int* blockhist = offs3 + (size_t)3 * (N_NODES + 1);          // 3*8*16*16384 = 24 MB
    int* cols      = blockhist + (size_t)3 * N_WIN * B_BLK * W_BINS; // 3*NEDGE

    tr_kernel<<<256, 256, 0, stream>>>(l1w1, wt_l1w1, 4);
    tr_kernel<<<256, 256, 0, stream>>>(l1w2, wt_l1w2, 4);
    tr_kernel<<<256, 256, 0, stream>>>(l2w1, wt_l2w1, 4);
    tr_kernel<<<256, 256, 0, stream>>>(l2w2, wt_l2w2, 4);
    tr_kernel<<<128, 256, 0, stream>>>(linw, wt_lin, 2);

    zero_kernel<<<64, 256, 0, stream>>>((floatx4*)out, (long)NGRAPH * 32);

    layer1_kernel<<<N_NODES / 128, 256, 0, stream>>>(
        x, rw, f1, f2, f3, wt_l1w1, l1b1, wt_l1w2, l1b2, x1b);

    // atomic-free CSR build for all 3 hops
    part_hist_kernel<<<3 * N_WIN * B_BLK, 256, 0, stream>>>(e1, e2, e3, blockhist);
    colscan_kernel<<<(3 * N_NODES + 255) / 256, 256, 0, stream>>>(blockhist, degs);
    scan3_kernel<<<3, 1024, 0, stream>>>(degs, offs3);
    scatter_ns_kernel<<<3 * N_WIN * B_BLK, 256, 0, stream>>>(
        e1, e2, e3, offs3, blockhist, cols);

    __bf16* ss[3] = {s1b, s2b, s3b};
    for (int hop = 0; hop < 3; ++hop) {
        csr_spmm_kernel<<<N_NODES / 4, 256, 0, stream>>>(
            offs3 + (size_t)hop * (N_NODES + 1), cols + (size_t)hop * NEDGE,
            x1b, ss[hop]);
    }

    layer2_kernel<<<N_NODES / 128, 256, 0, stream>>>(
        x1b, s1b, s2b, s3b, wt_l2w1, l2b1, wt_l2w2, l2b2, wt_lin, linb, batch, out);
}

// Round 6
// 1096.766 us; speedup vs baseline: 10.5102x; 1.4064x over previous
//
#include <hip/hip_runtime.h>

#define N_NODES 131072
#define DIM     128
#define NGRAPH  1024
#define NEDGE   4194304

#define NW      512                   // windows
#define WBINS   256                   // rows (bins) per window
#define NSL     256                   // edge slices per hop
#define SLICE_E (NEDGE / NSL)         // 16384 edges per slice
#define CAP     12288                 // LDS col-image capacity (ints); mean 8192

typedef float floatx4 __attribute__((ext_vector_type(4)));
typedef float f32x4  __attribute__((ext_vector_type(4)));
typedef __bf16 bf16x8 __attribute__((ext_vector_type(8)));
typedef __bf16 bf16x4 __attribute__((ext_vector_type(4)));

// swizzled LDS byte offset for a [rows][128] bf16 tile (row stride 256 B)
__device__ __forceinline__ int lds_off(int row, int kb) {
    return row * 256 + (kb ^ ((row & 7) << 4));
}

// ---------------------------------------------------------------- zero
__global__ __launch_bounds__(256)
void zero_kernel(floatx4* __restrict__ p, long n4) {
    long i = (long)blockIdx.x * blockDim.x + threadIdx.x;
    long stride = (long)gridDim.x * blockDim.x;
    floatx4 z = {0.f, 0.f, 0.f, 0.f};
    for (; i < n4; i += stride) p[i] = z;
}

// ---------------------------------------------------------------- weight prep
__global__ __launch_bounds__(256)
void tr_kernel(const float* __restrict__ src, __bf16* __restrict__ dst, int nmat) {
    int idx = blockIdx.x * blockDim.x + threadIdx.x;
    int total = nmat * 16384;
    if (idx >= total) return;
    int m = idx >> 14;
    int col = (idx >> 7) & 127;
    int k = idx & 127;
    dst[idx] = (__bf16)src[m * 16384 + k * 128 + col];
}

// ---------------------------------------------------------------- CSR build v2
// K1: per (hop,slice) LDS window-count (512 windows of 256 rows)
__global__ __launch_bounds__(256)
void wincount_kernel(const int* __restrict__ e1, const int* __restrict__ e2,
                     const int* __restrict__ e3, int* __restrict__ gcount) {
    const int gb = blockIdx.x;
    const int sl = gb % NSL;
    const int hop = gb / NSL;
    const int* rows = hop == 0 ? e1 : hop == 1 ? e2 : e3;

    __shared__ int cnt[NW];
    for (int i = threadIdx.x; i < NW; i += 256) cnt[i] = 0;
    __syncthreads();

    const int4* src = (const int4*)rows + (size_t)sl * (SLICE_E / 4);
    for (int j = threadIdx.x; j < SLICE_E / 4; j += 256) {
        int4 v = src[j];
        atomicAdd(&cnt[v.x >> 8], 1); atomicAdd(&cnt[v.y >> 8], 1);
        atomicAdd(&cnt[v.z >> 8], 1); atomicAdd(&cnt[v.w >> 8], 1);
    }
    __syncthreads();

    int* dst = gcount + ((size_t)hop * NSL + sl) * NW;
    for (int i = threadIdx.x; i < NW; i += 256) dst[i] = cnt[i];
}

// K2: per hop: window totals + scan -> wbase; per (window,slice) window-major bases
__global__ __launch_bounds__(256)
void basescan_kernel(const int* __restrict__ gcount, int* __restrict__ baseo,
                     int* __restrict__ wbase) {
    const int hop = blockIdx.x;
    const int t = threadIdx.x;
    __shared__ int wt[NW];
    __shared__ int part[256];

    for (int k = 0; k < 2; ++k) {
        int w = t * 2 + k;
        int s = 0;
        for (int sl = 0; sl < NSL; ++sl)
            s += gcount[((size_t)hop * NSL + sl) * NW + w];
        wt[w] = s;
    }
    __syncthreads();
    part[t] = wt[2 * t] + wt[2 * t + 1];
    __syncthreads();
    for (int d = 1; d < 256; d <<= 1) {
        int v = (t >= d) ? part[t - d] : 0;
        __syncthreads();
        part[t] += v;
        __syncthreads();
    }
    int run = (t == 0) ? 0 : part[t - 1];
    for (int k = 0; k < 2; ++k) {
        int w = 2 * t + k;
        wbase[hop * (NW + 1) + w] = run;
        int r2 = run;
        for (int sl = 0; sl < NSL; ++sl) {
            baseo[((size_t)hop * NW + w) * NSL + sl] = r2;
            r2 += gcount[((size_t)hop * NSL + sl) * NW + w];
        }
        run += wt[w];
    }
    if (t == 255) wbase[hop * (NW + 1) + NW] = NEDGE;
}

// K3: per (hop,slice): bucket edges into window-major buf, packed (binLocal<<17 | col)
__global__ __launch_bounds__(256)
void bucket_kernel(const int* __restrict__ e1, const int* __restrict__ e2,
                   const int* __restrict__ e3, const int* __restrict__ baseo,
                   int* __restrict__ buf) {
    const int gb = blockIdx.x;
    const int sl = gb % NSL;
    const int hop = gb / NSL;
    const int* rows = hop == 0 ? e1 : hop == 1 ? e2 : e3;
    const int* cs = rows + NEDGE;

    __shared__ int cur[NW];
    for (int i = threadIdx.x; i < NW; i += 256)
        cur[i] = baseo[((size_t)hop * NW + i) * NSL + sl];
    __syncthreads();

    int* b = buf + (size_t)hop * NEDGE;
    const int4* r4 = (const int4*)rows + (size_t)sl * (SLICE_E / 4);
    const int4* c4 = (const int4*)cs + (size_t)sl * (SLICE_E / 4);
    for (int j = threadIdx.x; j < SLICE_E / 4; j += 256) {
        int4 r = r4[j];
        int4 c = c4[j];
        int p;
        p = atomicAdd(&cur[r.x >> 8], 1); b[p] = ((r.x & 255) << 17) | c.x;
        p = atomicAdd(&cur[r.y >> 8], 1); b[p] = ((r.y & 255) << 17) | c.y;
        p = atomicAdd(&cur[r.z >> 8], 1); b[p] = ((r.z & 255) << 17) | c.z;
        p = atomicAdd(&cur[r.w >> 8], 1); b[p] = ((r.w & 255) << 17) | c.w;
    }
}

// K4: per (hop,window): build offs + bin-sorted col via LDS image; coalesced out
__global__ __launch_bounds__(256)
void winbuild_kernel(const int* __restrict__ buf, const int* __restrict__ wbase,
                     int* __restrict__ offs3, int* __restrict__ cols) {
    const int gb = blockIdx.x;
    const int w = gb % NW;
    const int hop = gb / NW;
    const int b0 = wbase[hop * (NW + 1) + w];
    const int b1 = wbase[hop * (NW + 1) + w + 1];
    const int tot = b1 - b0;
    const int* src = buf + (size_t)hop * NEDGE + b0;
    int* col = cols + (size_t)hop * NEDGE;
    int* offs = offs3 + (size_t)hop * (N_NODES + 1);
    const int t = threadIdx.x;

    __shared__ int hist[WBINS];
    __shared__ int scanb[WBINS];
    __shared__ int image[CAP];

    hist[t] = 0;
    __syncthreads();
    for (int i = t; i < tot; i += 256) atomicAdd(&hist[src[i] >> 17], 1);
    __syncthreads();

    // exclusive scan of hist[256]
    int v = hist[t];
    scanb[t] = v;
    __syncthreads();
    for (int d = 1; d < 256; d <<= 1) {
        int u = (t >= d) ? scanb[t - d] : 0;
        __syncthreads();
        scanb[t] += u;
        __syncthreads();
    }
    const int excl = scanb[t] - v;

    offs[w * WBINS + t] = b0 + excl;
    if (w == NW - 1 && t == 0) offs[N_NODES] = NEDGE;
    __syncthreads();

    if (tot <= CAP) {
        hist[t] = excl;                   // local cursors
        __syncthreads();
        for (int i = t; i < tot; i += 256) {
            int e = src[i];
            int p = atomicAdd(&hist[e >> 17], 1);
            image[p] = e & 0x1FFFF;
        }
        __syncthreads();
        for (int i = t; i < tot; i += 256) col[b0 + i] = image[i];
    } else {                              // overflow fallback (never expected)
        hist[t] = b0 + excl;
        __syncthreads();
        for (int i = t; i < tot; i += 256) {
            int e = src[i];
            int p = atomicAdd(&hist[e >> 17], 1);
            col[p] = e & 0x1FFFF;
        }
    }
}

// ---------------------------------------------------------------- CSR spmm (bf16)
__global__ __launch_bounds__(256)
void csr_spmm_kernel(const int* __restrict__ offs, const int* __restrict__ col,
                     const __bf16* __restrict__ xin, __bf16* __restrict__ outb) {
    const int lane = threadIdx.x & 63;
    const int row = blockIdx.x * (blockDim.x >> 6) + (threadIdx.x >> 6);
    if (row >= N_NODES) return;
    const int beg = offs[row];
    const int end = offs[row + 1];

    float a0 = 0.f, a1 = 0.f, b0 = 0.f, b1 = 0.f;
    float c0f = 0.f, c1f = 0.f, d0 = 0.f, d1 = 0.f;
    for (int b = beg; b < end; b += 64) {
        const int n = min(64, end - b);
        int cidx = (b + lane < end) ? col[b + lane] : 0;
        int i = 0;
        for (; i + 4 <= n; i += 4) {
            int e0 = __shfl(cidx, i);
            int e1 = __shfl(cidx, i + 1);
            int e2 = __shfl(cidx, i + 2);
            int e3 = __shfl(cidx, i + 3);
            unsigned v0 = *(const unsigned*)(xin + (size_t)e0 * 128 + lane * 2);
            unsigned v1 = *(const unsigned*)(xin + (size_t)e1 * 128 + lane * 2);
            unsigned v2 = *(const unsigned*)(xin + (size_t)e2 * 128 + lane * 2);
            unsigned v3 = *(const unsigned*)(xin + (size_t)e3 * 128 + lane * 2);
            a0 += __uint_as_float(v0 << 16); a1 += __uint_as_float(v0 & 0xffff0000u);
            b0 += __uint_as_float(v1 << 16); b1 += __uint_as_float(v1 & 0xffff0000u);
            c0f += __uint_as_float(v2 << 16); c1f += __uint_as_float(v2 & 0xffff0000u);
            d0 += __uint_as_float(v3 << 16); d1 += __uint_as_float(v3 & 0xffff0000u);
        }
        for (; i < n; ++i) {
            int e = __shfl(cidx, i);
            unsigned v = *(const unsigned*)(xin + (size_t)e * 128 + lane * 2);
            a0 += __uint_as_float(v << 16); a1 += __uint_as_float(v & 0xffff0000u);
        }
    }
    float o0 = a0 + b0 + c0f + d0;
    float o1 = a1 + b1 + c1f + d1;
    union { unsigned u; __bf16 h[2]; } pk;
    pk.h[0] = (__bf16)o0; pk.h[1] = (__bf16)o1;
    *(unsigned*)(outb + (size_t)row * 128 + lane * 2) = pk.u;
}

// ---------------------------------------------------------------- staging helpers
__device__ __forceinline__ void stage_bf16_tile(char* dst, const __bf16* src, int tid) {
#pragma unroll
    for (int it = 0; it < 8; ++it) {
        int c = tid + it * 256;
        int r = c >> 4, o = c & 15;
        uint4 v = *(const uint4*)(src + (size_t)r * 128 + o * 8);
        *(uint4*)(dst + lds_off(r, o * 16)) = v;
    }
}

__device__ __forceinline__ void stage_f32_tile(char* dst, const float* src, int tid) {
#pragma unroll
    for (int it = 0; it < 16; ++it) {
        int c = tid + it * 256;
        int r = c >> 5, o = c & 31;
        floatx4 v = *(const floatx4*)(src + (size_t)r * 128 + o * 4);
        bf16x4 h;
        h[0] = (__bf16)v[0]; h[1] = (__bf16)v[1];
        h[2] = (__bf16)v[2]; h[3] = (__bf16)v[3];
        *(bf16x4*)(dst + lds_off(r, o * 8)) = h;
    }
}

__device__ __forceinline__ void mfma_phase(const char* az, const char* wb,
                                           int r0, int lrow, int grp,
                                           f32x4 (&acc)[2][8]) {
    bf16x8 am[2][4];
#pragma unroll
    for (int mt = 0; mt < 2; ++mt)
#pragma unroll
        for (int kk = 0; kk < 4; ++kk)
            am[mt][kk] = *(const bf16x8*)(az + lds_off(r0 + mt * 16 + lrow,
                                                       kk * 64 + grp * 16));
#pragma unroll
    for (int kk = 0; kk < 4; ++kk)
#pragma unroll
        for (int n = 0; n < 8; ++n) {
            bf16x8 b = *(const bf16x8*)(wb + lds_off(n * 16 + lrow,
                                                     kk * 64 + grp * 16));
#pragma unroll
            for (int mt = 0; mt < 2; ++mt)
                acc[mt][n] = __builtin_amdgcn_mfma_f32_16x16x32_bf16(
                    am[mt][kk], b, acc[mt][n], 0, 0, 0);
        }
}

// ---------------------------------------------------------------- layer 1 (MFMA)
__global__ __launch_bounds__(256, 2)
void layer1_kernel(const float* __restrict__ x, const float* __restrict__ rw,
                   const float* __restrict__ f1, const float* __restrict__ f2,
                   const float* __restrict__ f3,
                   const __bf16* __restrict__ wt1, const float* __restrict__ b1,
                   const __bf16* __restrict__ wt2, const float* __restrict__ b2,
                   __bf16* __restrict__ x1out)
{
    __shared__ uint4 lds_u4[4096];
    char* AZ = (char*)lds_u4;
    char* WB = (char*)lds_u4 + 32768;
    const int tid = threadIdx.x;
    const int lane = tid & 63;
    const int w = tid >> 6;
    const int r0 = w * 32;
    const int lrow = lane & 15;
    const int grp = lane >> 4;
    const int row0 = blockIdx.x * 128;

    f32x4 Y[2][8];
#pragma unroll
    for (int mt = 0; mt < 2; ++mt)
#pragma unroll
        for (int n = 0; n < 8; ++n) Y[mt][n] = {0.f, 0.f, 0.f, 0.f};

    for (int h = 0; h < 4; ++h) {
        __syncthreads();
        if (h == 0) {
#pragma unroll
            for (int it = 0; it < 16; ++it) {
                int c = tid + it * 256;
                int r = c >> 5, o = c & 31;
                const float* src = (o < 16)
                    ? (x  + (size_t)(row0 + r) * 64 + o * 4)
                    : (rw + (size_t)(row0 + r) * 64 + (o - 16) * 4);
                floatx4 v = *(const floatx4*)src;
                bf16x4 hh;
                hh[0] = (__bf16)v[0]; hh[1] = (__bf16)v[1];
                hh[2] = (__bf16)v[2]; hh[3] = (__bf16)v[3];
                *(bf16x4*)(AZ + lds_off(r, o * 8)) = hh;
            }
        } else {
            const float* feat = (h == 1) ? f1 : (h == 2) ? f2 : f3;
            stage_f32_tile(AZ, feat + (size_t)row0 * 128, tid);
        }
        stage_bf16_tile(WB, wt1 + (size_t)h * 16384, tid);
        __syncthreads();

        f32x4 acc1[2][8];
#pragma unroll
        for (int mt = 0; mt < 2; ++mt)
#pragma unroll
            for (int n = 0; n < 8; ++n) acc1[mt][n] = {0.f, 0.f, 0.f, 0.f};
        mfma_phase(AZ, WB, r0, lrow, grp, acc1);

#pragma unroll
        for (int n = 0; n < 8; ++n) {
            float bias = b1[h * 128 + n * 16 + lrow];
#pragma unroll
            for (int mt = 0; mt < 2; ++mt)
#pragma unroll
                for (int rg = 0; rg < 4; ++rg) {
                    float v = fmaxf(acc1[mt][n][rg] + bias, 0.f);
                    int zr = r0 + mt * 16 + grp * 4 + rg;
                    *(__bf16*)(AZ + lds_off(zr, (n * 16 + lrow) * 2)) = (__bf16)v;
                }
        }
        __syncthreads();
        stage_bf16_tile(WB, wt2 + (size_t)h * 16384, tid);
        __syncthreads();
        mfma_phase(AZ, WB, r0, lrow, grp, Y);
    }

#pragma unroll
    for (int n = 0; n < 8; ++n) {
        int cc = n * 16 + lrow;
        float bs = b2[cc] + b2[128 + cc] + b2[256 + cc] + b2[384 + cc];
#pragma unroll
        for (int mt = 0; mt < 2; ++mt)
#pragma unroll
            for (int rg = 0; rg < 4; ++rg) {
                int gr = row0 + r0 + mt * 16 + grp * 4 + rg;
                x1out[(size_t)gr * 128 + cc] = (__bf16)(Y[mt][n][rg] + bs);
            }
    }
}

// ---------------------------------------------------------------- layer 2 + lin + pool (MFMA)
__global__ __launch_bounds__(256, 2)
void layer2_kernel(const __bf16* __restrict__ x1b, const __bf16* __restrict__ s1,
                   const __bf16* __restrict__ s2, const __bf16* __restrict__ s3,
                   const __bf16* __restrict__ wt1, const float* __restrict__ b1,
                   const __bf16* __restrict__ wt2, const float* __restrict__ b2,
                   const __bf16* __restrict__ wtl, const float* __restrict__ linb,
                   const int* __restrict__ batch, float* __restrict__ dout)
{
    __shared__ uint4 lds_u4[4096];
    char* AZ = (char*)lds_u4;
    char* WB = (char*)lds_u4 + 32768;
    const int tid = threadIdx.x;
    const int lane = tid & 63;
    const int w = tid >> 6;
    const int r0 = w * 32;
    const int lrow = lane & 15;
    const int grp = lane >> 4;
    const int row0 = blockIdx.x * 128;

    f32x4 Y[2][8];
#pragma unroll
    for (int mt = 0; mt < 2; ++mt)
#pragma unroll
        for (int n = 0; n < 8; ++n) Y[mt][n] = {0.f, 0.f, 0.f, 0.f};

    for (int h = 0; h < 4; ++h) {
        const __bf16* feat = (h == 0) ? x1b : (h == 1) ? s1 : (h == 2) ? s2 : s3;
        __syncthreads();
        stage_bf16_tile(AZ, feat + (size_t)row0 * 128, tid);
        stage_bf16_tile(WB, wt1 + (size_t)h * 16384, tid);
        __syncthreads();

        f32x4 acc1[2][8];
#pragma unroll
        for (int mt = 0; mt < 2; ++mt)
#pragma unroll
            for (int n = 0; n < 8; ++n) acc1[mt][n] = {0.f, 0.f, 0.f, 0.f};
        mfma_phase(AZ, WB, r0, lrow, grp, acc1);

#pragma unroll
        for (int n = 0; n < 8; ++n) {
            float bias = b1[h * 128 + n * 16 + lrow];
#pragma unroll
            for (int mt = 0; mt < 2; ++mt)
#pragma unroll
                for (int rg = 0; rg < 4; ++rg) {
                    float v = fmaxf(acc1[mt][n][rg] + bias, 0.f);
                    int zr = r0 + mt * 16 + grp * 4 + rg;
                    *(__bf16*)(AZ + lds_off(zr, (n * 16 + lrow) * 2)) = (__bf16)v;
                }
        }
        __syncthreads();
        stage_bf16_tile(WB, wt2 + (size_t)h * 16384, tid);
        __syncthreads();
        mfma_phase(AZ, WB, r0, lrow, grp, Y);
    }

#pragma unroll
    for (int n = 0; n < 8; ++n) {
        int cc = n * 16 + lrow;
        float bs = b2[cc] + b2[128 + cc] + b2[256 + cc] + b2[384 + cc];
#pragma unroll
        for (int mt = 0; mt < 2; ++mt)
#pragma unroll
            for (int rg = 0; rg < 4; ++rg) {
                float v = Y[mt][n][rg] + bs;
                int zr = r0 + mt * 16 + grp * 4 + rg;
                *(__bf16*)(AZ + lds_off(zr, (n * 16 + lrow) * 2)) = (__bf16)v;
            }
    }
    __syncthreads();
    stage_bf16_tile(WB, wtl + 16384, tid);
    __syncthreads();

    f32x4 o[2][8];
#pragma unroll
    for (int mt = 0; mt < 2; ++mt)
#pragma unroll
        for (int n = 0; n < 8; ++n) o[mt][n] = {0.f, 0.f, 0.f, 0.f};
    mfma_phase(AZ, WB, r0, lrow, grp, o);

    __syncthreads();
    stage_bf16_tile(AZ, x1b + (size_t)row0 * 128, tid);
    stage_bf16_tile(WB, wtl, tid);
    __syncthreads();
    mfma_phase(AZ, WB, r0, lrow, grp, o);

    __syncthreads();
    float* tile32 = (float*)lds_u4;
#pragma unroll
    for (int n = 0; n < 8; ++n) {
        int cc = n * 16 + lrow;
        float lb = linb[cc];
#pragma unroll
        for (int mt = 0; mt < 2; ++mt)
#pragma unroll
            for (int rg = 0; rg < 4; ++rg) {
                int rl = r0 + mt * 16 + grp * 4 + rg;
                tile32[rl * 128 + cc] = o[mt][n][rg] + lb;
            }
    }
    __syncthreads();

    if (tid < 128) {
        const int d = tid;
        float acc = 0.f;
        int cur = batch[row0];
        for (int r = 0; r < 128; ++r) {
            int b = batch[row0 + r];
            if (b != cur) {
                atomicAdd(dout + (size_t)cur * 128 + d, acc);
                acc = 0.f;
                cur = b;
            }
            acc += tile32[r * 128 + d];
        }
        atomicAdd(dout + (size_t)cur * 128 + d, acc);
    }
}

// ---------------------------------------------------------------- launch
extern "C" void kernel_launch(void* const* d_in, const int* in_sizes, int n_in,
                              void* d_out, int out_size, void* d_ws, size_t ws_size,
                              hipStream_t stream) {
    (void)in_sizes; (void)n_in; (void)out_size; (void)ws_size;

    const float* x    = (const float*)d_in[0];
    const float* rw   = (const float*)d_in[1];
    const float* f1   = (const float*)d_in[2];
    const float* f2   = (const float*)d_in[3];
    const float* f3   = (const float*)d_in[4];
    const int*   e1   = (const int*)d_in[5];
    const int*   e2   = (const int*)d_in[6];
    const int*   e3   = (const int*)d_in[7];
    const int*   batch= (const int*)d_in[8];
    const float* l1w1 = (const float*)d_in[9];
    const float* l1b1 = (const float*)d_in[10];
    const float* l1w2 = (const float*)d_in[11];
    const float* l1b2 = (const float*)d_in[12];
    const float* l2w1 = (const float*)d_in[13];
    const float* l2b1 = (const float*)d_in[14];
    const float* l2w2 = (const float*)d_in[15];
    const float* l2b2 = (const float*)d_in[16];
    const float* linw = (const float*)d_in[17];
    const float* linb = (const float*)d_in[18];

    float* out = (float*)d_out;

    // workspace layout
    __bf16* x1b = (__bf16*)d_ws;
    __bf16* s1b = x1b + (size_t)N_NODES * 128;
    __bf16* s2b = s1b + (size_t)N_NODES * 128;
    __bf16* s3b = s2b + (size_t)N_NODES * 128;
    __bf16* wt  = s3b + (size_t)N_NODES * 128;
    __bf16* wt_l1w1 = wt;
    __bf16* wt_l1w2 = wt + 4 * 16384;
    __bf16* wt_l2w1 = wt + 8 * 16384;
    __bf16* wt_l2w2 = wt + 12 * 16384;
    __bf16* wt_lin  = wt + 16 * 16384;
    int* ibase  = (int*)(wt + 18 * 16384);
    int* offs3  = ibase;                                    // 3*(N+1)
    int* gcount = offs3 + (size_t)3 * (N_NODES + 1);        // 3*NSL*NW
    int* baseo  = gcount + (size_t)3 * NSL * NW;            // 3*NW*NSL
    int* wbase  = baseo + (size_t)3 * NW * NSL;             // 3*(NW+1)
    int* buf    = wbase + (size_t)3 * (NW + 1);             // 3*NEDGE (packed)
    int* cols   = buf + (size_t)3 * NEDGE;                  // 3*NEDGE

    tr_kernel<<<256, 256, 0, stream>>>(l1w1, wt_l1w1, 4);
    tr_kernel<<<256, 256, 0, stream>>>(l1w2, wt_l1w2, 4);
    tr_kernel<<<256, 256, 0, stream>>>(l2w1, wt_l2w1, 4);
    tr_kernel<<<256, 256, 0, stream>>>(l2w2, wt_l2w2, 4);
    tr_kernel<<<128, 256, 0, stream>>>(linw, wt_lin, 2);

    zero_kernel<<<64, 256, 0, stream>>>((floatx4*)out, (long)NGRAPH * 32);

    layer1_kernel<<<N_NODES / 128, 256, 0, stream>>>(
        x, rw, f1, f2, f3, wt_l1w1, l1b1, wt_l1w2, l1b2, x1b);

    // CSR build v2: two-level counting sort, coalesced col assembly
    wincount_kernel<<<3 * NSL, 256, 0, stream>>>(e1, e2, e3, gcount);
    basescan_kernel<<<3, 256, 0, stream>>>(gcount, baseo, wbase);
    bucket_kernel<<<3 * NSL, 256, 0, stream>>>(e1, e2, e3, baseo, buf);
    winbuild_kernel<<<3 * NW, 256, 0, stream>>>(buf, wbase, offs3, cols);

    __bf16* ss[3] = {s1b, s2b, s3b};
    for (int hop = 0; hop < 3; ++hop) {
        csr_spmm_kernel<<<N_NODES / 4, 256, 0, stream>>>(
            offs3 + (size_t)hop * (N_NODES + 1), cols + (size_t)hop * NEDGE,
            x1b, ss[hop]);
    }

    layer2_kernel<<<N_NODES / 128, 256, 0, stream>>>(
        x1b, s1b, s2b, s3b, wt_l2w1, l2b1, wt_l2w2, l2b2, wt_lin, linb, batch, out);
}